// Round 13
// baseline (434.933 us; speedup 1.0000x reference)
//
#include <hip/hip_runtime.h>
#include <hip/hip_bf16.h>
#include <math.h>

// Problem dims (fixed): T=512, B=256, I=128, H=256
#define TT 512
#define BB 256
#define II 128
#define HH 256

// 2*log2(e): Wh and xi pre-scaled so tanh is exp2-direct.
#define TANH_S 2.885390043258667f

// ---------------------------------------------------------------------------
// Kernel 1: input projection  xi[m][n] = (sum_k x[m][k]*Wi[n][k] + bh[n]) * S
//   Split-K staging: two 64-k halves -> LDS 33KB -> 4 blocks/CU.
// ---------------------------------------------------------------------------
__global__ __launch_bounds__(256) void proj_kernel(
    const float* __restrict__ x, const float* __restrict__ Wi,
    const float* __restrict__ bh, float* __restrict__ out)
{
    __shared__ float xt[64][68];
    __shared__ float wt[64][64];

    const int tid = threadIdx.x;
    const int m0 = blockIdx.x * 64;
    const int j0 = blockIdx.y * 64;
    const int ty = tid >> 4, tx = tid & 15;
    const int r0 = ty * 4;

    float acc[4][4] = {};

#pragma unroll
    for (int half = 0; half < 2; ++half) {
        if (half) __syncthreads();   // protect restage vs previous reads
        {
            const int r  = tid & 63;
            const int kc = tid >> 6;             // 0..3 -> 16 k each
            const float* xsrc = x  + (size_t)(m0 + r) * II + half * 64 + kc * 16;
            const float* wsrc = Wi + (size_t)(j0 + r) * II + half * 64 + kc * 16;
#pragma unroll
            for (int u = 0; u < 4; ++u) {
                float4 v = *(const float4*)(xsrc + u * 4);
                int k = kc * 16 + u * 4;
                xt[k + 0][r] = v.x; xt[k + 1][r] = v.y;
                xt[k + 2][r] = v.z; xt[k + 3][r] = v.w;
            }
#pragma unroll
            for (int u = 0; u < 4; ++u) {
                float4 v = *(const float4*)(wsrc + u * 4);
                int k = kc * 16 + u * 4;
                wt[k + 0][r] = v.x; wt[k + 1][r] = v.y;
                wt[k + 2][r] = v.z; wt[k + 3][r] = v.w;
            }
        }
        __syncthreads();

        const float* xp = &xt[0][r0];
        const float* wp = &wt[0][tx * 4];
#pragma unroll
        for (int kk = 0; kk < 64; kk += 8) {
            float4 av[8], bv[8];
#pragma unroll
            for (int u = 0; u < 8; ++u) {
                av[u] = *(const float4*)(xp + (size_t)(kk + u) * 68);
                bv[u] = *(const float4*)(wp + (size_t)(kk + u) * 64);
            }
#pragma unroll
            for (int u = 0; u < 8; ++u) {
                float a4[4] = {av[u].x, av[u].y, av[u].z, av[u].w};
                float b4[4] = {bv[u].x, bv[u].y, bv[u].z, bv[u].w};
#pragma unroll
                for (int i = 0; i < 4; ++i)
#pragma unroll
                    for (int j = 0; j < 4; ++j)
                        acc[i][j] += a4[i] * b4[j];
            }
        }
    }

    float4 bias = *(const float4*)(bh + j0 + tx * 4);
    float bvv[4] = {bias.x, bias.y, bias.z, bias.w};
#pragma unroll
    for (int i = 0; i < 4; ++i) {
        float4 o;
        o.x = (acc[i][0] + bvv[0]) * TANH_S;
        o.y = (acc[i][1] + bvv[1]) * TANH_S;
        o.z = (acc[i][2] + bvv[2]) * TANH_S;
        o.w = (acc[i][3] + bvv[3]) * TANH_S;
        *(float4*)(out + (size_t)(m0 + r0 + i) * HH + j0 + tx * 4) = o;
    }
}

// ---------------------------------------------------------------------------
// Kernel 2: recurrence, 1024 threads = 16 waves (4 waves/SIMD).
//   Wave q owns cols [16q,+16). Lane l: kg = l bits{0,1,3,5} (16 k-groups of
//   16 k), cg = l bits{2,4} (4 col-quads). Thread = 4 cols x 16 k.
//   Wh frag (4col x 16k, PRE-SCALED by 2log2e) = 64 floats in v64-v127.
//   h LDS: 16 groups x 80B stride (16-B aligned; 2-way bank alias = free).
//   Double-buffered at +0x800, one barrier/step.
//   Reduce: merge -> xor1+xor2 (DPP) -> select-early (3 cndmask by kg&3)
//   -> **s_nop 1** -> xor8 (row_ror:8) -> xor32 via ds_bpermute.
//   THE r11/r12 BUG: DPP needs 2 wait states after a VALU write to its
//   crossbar-read source; select-early put cndmask(v28) 0 instructions
//   before row_ror(v28) -> garbage lanes (absmax ~1.9). r8-r10 never hit
//   this because their select came after all DPP ops (>=3-instr gaps).
//   xi prefetched one step ahead (vmcnt(2)); stores masked to kg<4 lanes.
// ---------------------------------------------------------------------------

#define RNN16_BODY(XN, XC) \
        "ds_read_b128 v[40:43], v58\n" \
        "ds_read_b128 v[44:47], v58 offset:16\n" \
        "ds_read_b128 v[48:51], v58 offset:32\n" \
        "ds_read_b128 v[52:55], v58 offset:48\n" \
        "v_xor_b32 v58, 0x800, v58\n" \
        "global_load_dword " XN ", v60, %[iob]\n" \
        "v_add_u32 v60, 0x40000, v60\n" \
        "v_min_u32 v60, %[viomax], v60\n" \
        /* m=0 */ \
        "s_waitcnt lgkmcnt(3)\n" \
        "v_pk_mul_f32 v[32:33], v[64:65],   v[40:41]\n" \
        "v_pk_mul_f32 v[34:35], v[80:81],   v[40:41]\n" \
        "v_pk_mul_f32 v[36:37], v[96:97],   v[40:41]\n" \
        "v_pk_mul_f32 v[38:39], v[112:113], v[40:41]\n" \
        "v_pk_fma_f32 v[32:33], v[66:67],   v[42:43], v[32:33]\n" \
        "v_pk_fma_f32 v[34:35], v[82:83],   v[42:43], v[34:35]\n" \
        "v_pk_fma_f32 v[36:37], v[98:99],   v[42:43], v[36:37]\n" \
        "v_pk_fma_f32 v[38:39], v[114:115], v[42:43], v[38:39]\n" \
        /* m=1 */ \
        "s_waitcnt lgkmcnt(2)\n" \
        "v_pk_fma_f32 v[32:33], v[68:69],   v[44:45], v[32:33]\n" \
        "v_pk_fma_f32 v[34:35], v[84:85],   v[44:45], v[34:35]\n" \
        "v_pk_fma_f32 v[36:37], v[100:101], v[44:45], v[36:37]\n" \
        "v_pk_fma_f32 v[38:39], v[116:117], v[44:45], v[38:39]\n" \
        "v_pk_fma_f32 v[32:33], v[70:71],   v[46:47], v[32:33]\n" \
        "v_pk_fma_f32 v[34:35], v[86:87],   v[46:47], v[34:35]\n" \
        "v_pk_fma_f32 v[36:37], v[102:103], v[46:47], v[36:37]\n" \
        "v_pk_fma_f32 v[38:39], v[118:119], v[46:47], v[38:39]\n" \
        /* m=2 */ \
        "s_waitcnt lgkmcnt(1)\n" \
        "v_pk_fma_f32 v[32:33], v[72:73],   v[48:49], v[32:33]\n" \
        "v_pk_fma_f32 v[34:35], v[88:89],   v[48:49], v[34:35]\n" \
        "v_pk_fma_f32 v[36:37], v[104:105], v[48:49], v[36:37]\n" \
        "v_pk_fma_f32 v[38:39], v[120:121], v[48:49], v[38:39]\n" \
        "v_pk_fma_f32 v[32:33], v[74:75],   v[50:51], v[32:33]\n" \
        "v_pk_fma_f32 v[34:35], v[90:91],   v[50:51], v[34:35]\n" \
        "v_pk_fma_f32 v[36:37], v[106:107], v[50:51], v[36:37]\n" \
        "v_pk_fma_f32 v[38:39], v[122:123], v[50:51], v[38:39]\n" \
        /* m=3 */ \
        "s_waitcnt lgkmcnt(0)\n" \
        "v_pk_fma_f32 v[32:33], v[76:77],   v[52:53], v[32:33]\n" \
        "v_pk_fma_f32 v[34:35], v[92:93],   v[52:53], v[34:35]\n" \
        "v_pk_fma_f32 v[36:37], v[108:109], v[52:53], v[36:37]\n" \
        "v_pk_fma_f32 v[38:39], v[124:125], v[52:53], v[38:39]\n" \
        "v_pk_fma_f32 v[32:33], v[78:79],   v[54:55], v[32:33]\n" \
        "v_pk_fma_f32 v[34:35], v[94:95],   v[54:55], v[34:35]\n" \
        "v_pk_fma_f32 v[36:37], v[110:111], v[54:55], v[36:37]\n" \
        "v_pk_fma_f32 v[38:39], v[126:127], v[54:55], v[38:39]\n" \
        /* merge pk pairs -> 4 col sums */ \
        "v_add_f32 v24, v32, v33\n" \
        "v_add_f32 v25, v34, v35\n" \
        "v_add_f32 v26, v36, v37\n" \
        "v_add_f32 v27, v38, v39\n" \
        /* xor1, xor2 over kg bits 0,1 (each DPP src has >=3-instr gap) */ \
        "v_add_f32 v24, v24, v24 quad_perm:[1,0,3,2] row_mask:0xf bank_mask:0xf\n" \
        "v_add_f32 v25, v25, v25 quad_perm:[1,0,3,2] row_mask:0xf bank_mask:0xf\n" \
        "v_add_f32 v26, v26, v26 quad_perm:[1,0,3,2] row_mask:0xf bank_mask:0xf\n" \
        "v_add_f32 v27, v27, v27 quad_perm:[1,0,3,2] row_mask:0xf bank_mask:0xf\n" \
        "v_add_f32 v24, v24, v24 quad_perm:[2,3,0,1] row_mask:0xf bank_mask:0xf\n" \
        "v_add_f32 v25, v25, v25 quad_perm:[2,3,0,1] row_mask:0xf bank_mask:0xf\n" \
        "v_add_f32 v26, v26, v26 quad_perm:[2,3,0,1] row_mask:0xf bank_mask:0xf\n" \
        "v_add_f32 v27, v27, v27 quad_perm:[2,3,0,1] row_mask:0xf bank_mask:0xf\n" \
        /* select-early: this lane's column (kg&3) */ \
        "v_cndmask_b32 v28, v24, v25, %[m0]\n" \
        "v_cndmask_b32 v29, v26, v27, %[m0]\n" \
        "v_cndmask_b32 v28, v28, v29, %[m1]\n" \
        /* DPP hazard fence: 2 wait states before row_ror reads v28 */ \
        "s_nop 1\n" \
        /* xor8 (kg bit2 = lane bit3) */ \
        "v_add_f32 v28, v28, v28 row_ror:8 row_mask:0xf bank_mask:0xf\n" \
        /* xor32 (kg bit3 = lane bit5) via ds_bpermute (interlocked) */ \
        "ds_bpermute_b32 v29, %[ba], v28\n" \
        "s_waitcnt lgkmcnt(0)\n" \
        "v_add_f32 v28, v28, v29\n" \
        /* + xi (pre-scaled, prefetched last step) */ \
        "s_waitcnt vmcnt(2)\n" \
        "v_add_f32 v28, v28, " XC "\n" \
        /* tanh = 1 - 2*rcp(exp2(arg)+1) */ \
        "v_exp_f32 v24, v28\n" \
        "s_nop 0\n" \
        "v_add_f32 v24, 1.0, v24\n" \
        "v_rcp_f32 v24, v24\n" \
        "s_nop 0\n" \
        "v_fma_f32 v28, -2.0, v24, 1.0\n" \
        /* masked stores (kg<4 = one writer per column) */ \
        "s_and_saveexec_b64 s[84:85], %[msk]\n" \
        "ds_write_b32 v59, v28\n" \
        "global_store_dword v61, v28, %[iob]\n" \
        "s_mov_b64 exec, s[84:85]\n" \
        "v_xor_b32 v59, 0x800, v59\n" \
        "v_add_u32 v61, 0x40000, v61\n" \
        "s_waitcnt lgkmcnt(0)\n" \
        "s_barrier\n"

#define SCALE_PAIR(P) "v_pk_mul_f32 v[" P "], v[" P "], v[26:27]\n"

__global__ __launch_bounds__(1024) void rec_kernel(
    const float* __restrict__ Wh, const float* __restrict__ h0,
    float* __restrict__ io)
{
    __shared__ float hbuf[832];  // buf0 [0,1280) buf1 [0x800,+1280)

    const int tid  = threadIdx.x;
    const int b    = blockIdx.x;
    const int lane = tid & 63;
    const int q    = tid >> 6;                        // wave id 0..15
    const int kg   = (lane & 3) | ((lane >> 1) & 4) | ((lane >> 2) & 8);
    const int cg   = ((lane >> 2) & 1) | ((lane >> 3) & 2);
    const int col0 = 16 * q + 4 * cg;
    const int col  = col0 + (kg & 3);

    const float* wp  = Wh + (size_t)col0 * HH + kg * 16;
    const float* iob = io + (size_t)b * HH;
    unsigned hbase = (unsigned)(size_t)&hbuf[0];
    unsigned hvr = hbase + kg * 80;                   // read base (buf0), 16B-aligned
    unsigned hvw = hbase + 0x800 + q * 80 + (4 * cg + (kg & 3)) * 4;
    unsigned vio = (unsigned)(col * 4);
    unsigned viomax = vio + 511u * 0x40000u;
    unsigned ba  = (unsigned)((lane ^ 32) << 2);      // bpermute addr
    unsigned long long m0 = __ballot((lane & 1) != 0);
    unsigned long long m1 = __ballot((lane & 2) != 0);
    unsigned long long msk = __ballot(kg < 4);        // writer lanes

    if (tid < HH) hbuf[(tid >> 4) * 20 + (tid & 15)] = h0[(size_t)b * HH + tid];
    __syncthreads();

    asm volatile(
        // ---- Wh fragment: row j (col0+j) quad m -> v[64+16j+4m] ----
        "global_load_dwordx4 v[64:67],   %[wp], off\n"
        "global_load_dwordx4 v[68:71],   %[wp], off offset:16\n"
        "global_load_dwordx4 v[72:75],   %[wp], off offset:32\n"
        "global_load_dwordx4 v[76:79],   %[wp], off offset:48\n"
        "global_load_dwordx4 v[80:83],   %[wp], off offset:1024\n"
        "global_load_dwordx4 v[84:87],   %[wp], off offset:1040\n"
        "global_load_dwordx4 v[88:91],   %[wp], off offset:1056\n"
        "global_load_dwordx4 v[92:95],   %[wp], off offset:1072\n"
        "global_load_dwordx4 v[96:99],   %[wp], off offset:2048\n"
        "global_load_dwordx4 v[100:103], %[wp], off offset:2064\n"
        "global_load_dwordx4 v[104:107], %[wp], off offset:2080\n"
        "global_load_dwordx4 v[108:111], %[wp], off offset:2096\n"
        "global_load_dwordx4 v[112:115], %[wp], off offset:3072\n"
        "global_load_dwordx4 v[116:119], %[wp], off offset:3088\n"
        "global_load_dwordx4 v[120:123], %[wp], off offset:3104\n"
        "global_load_dwordx4 v[124:127], %[wp], off offset:3120\n"
        // ---- init + xi_0 prologue load ----
        "v_mov_b32 v58, %[hvr]\n"
        "v_mov_b32 v59, %[hvw]\n"
        "v_mov_b32 v60, %[vio]\n"
        "v_mov_b32 v61, %[vio]\n"
        "global_load_dword v57, v60, %[iob]\n"
        "v_add_u32 v60, 0x40000, v60\n"
        "s_movk_i32 s82, 0x100\n"
        "s_waitcnt vmcnt(0)\n"
        // ---- one-time pre-scale of Wh fragment by 2*log2(e) ----
        "v_mov_b32 v26, 0x4038aa3b\n"
        "v_mov_b32 v27, 0x4038aa3b\n"
        SCALE_PAIR("64:65")   SCALE_PAIR("66:67")   SCALE_PAIR("68:69")   SCALE_PAIR("70:71")
        SCALE_PAIR("72:73")   SCALE_PAIR("74:75")   SCALE_PAIR("76:77")   SCALE_PAIR("78:79")
        SCALE_PAIR("80:81")   SCALE_PAIR("82:83")   SCALE_PAIR("84:85")   SCALE_PAIR("86:87")
        SCALE_PAIR("88:89")   SCALE_PAIR("90:91")   SCALE_PAIR("92:93")   SCALE_PAIR("94:95")
        SCALE_PAIR("96:97")   SCALE_PAIR("98:99")   SCALE_PAIR("100:101") SCALE_PAIR("102:103")
        SCALE_PAIR("104:105") SCALE_PAIR("106:107") SCALE_PAIR("108:109") SCALE_PAIR("110:111")
        SCALE_PAIR("112:113") SCALE_PAIR("114:115") SCALE_PAIR("116:117") SCALE_PAIR("118:119")
        SCALE_PAIR("120:121") SCALE_PAIR("122:123") SCALE_PAIR("124:125") SCALE_PAIR("126:127")
        "LTOP_%=:\n"
        RNN16_BODY("v56", "v57")
        RNN16_BODY("v57", "v56")
        "s_sub_u32 s82, s82, 1\n"
        "s_cmp_lg_u32 s82, 0\n"
        "s_cbranch_scc1 LTOP_%=\n"
        :
        : [wp] "v"(wp), [iob] "s"(iob),
          [hvr] "v"(hvr), [hvw] "v"(hvw), [vio] "v"(vio),
          [viomax] "v"(viomax), [ba] "v"(ba),
          [m0] "s"(m0), [m1] "s"(m1), [msk] "s"(msk)
        : "memory", "scc", "s82", "s84", "s85",
          "v24","v25","v26","v27","v28","v29","v30","v31",
          "v32","v33","v34","v35","v36","v37","v38","v39",
          "v40","v41","v42","v43","v44","v45","v46","v47",
          "v48","v49","v50","v51","v52","v53","v54","v55",
          "v56","v57","v58","v59","v60","v61","v62","v63",
          "v64","v65","v66","v67","v68","v69","v70","v71",
          "v72","v73","v74","v75","v76","v77","v78","v79",
          "v80","v81","v82","v83","v84","v85","v86","v87",
          "v88","v89","v90","v91","v92","v93","v94","v95",
          "v96","v97","v98","v99","v100","v101","v102","v103",
          "v104","v105","v106","v107","v108","v109","v110","v111",
          "v112","v113","v114","v115","v116","v117","v118","v119",
          "v120","v121","v122","v123","v124","v125","v126","v127");
}

extern "C" void kernel_launch(void* const* d_in, const int* in_sizes, int n_in,
                              void* d_out, int out_size, void* d_ws, size_t ws_size,
                              hipStream_t stream) {
    const float* x  = (const float*)d_in[0];  // [T,B,I]
    const float* h0 = (const float*)d_in[1];  // [B,H]
    const float* Wi = (const float*)d_in[2];  // [H,I]
    const float* Wh = (const float*)d_in[3];  // [H,H]
    const float* bh = (const float*)d_in[4];  // [H]
    float* out = (float*)d_out;               // [T,B,H]

    dim3 pgrid(TT * BB / 64, HH / 64);
    proj_kernel<<<pgrid, 256, 0, stream>>>(x, Wi, bh, out);
    rec_kernel<<<BB, 1024, 0, stream>>>(Wh, h0, out);
}

// Round 14
// 392.106 us; speedup vs baseline: 1.1092x; 1.1092x over previous
//
#include <hip/hip_runtime.h>
#include <hip/hip_bf16.h>
#include <math.h>

// Problem dims (fixed): T=512, B=256, I=128, H=256
#define TT 512
#define BB 256
#define II 128
#define HH 256

// 2*log2(e): Wh and xi pre-scaled so tanh is exp2-direct.
#define TANH_S 2.885390043258667f

// ---------------------------------------------------------------------------
// Kernel 1: input projection  xi[m][n] = (sum_k x[m][k]*Wi[n][k] + bh[n]) * S
//   Split-K staging (r13-proven): two 64-k halves -> LDS 33KB -> 4 blocks/CU
//   (16 waves/CU; the monolithic 66KB version was latency-exposed at
//   2 blocks/CU: 99us vs 55us fp32-issue floor; this one measured ~79us).
// ---------------------------------------------------------------------------
__global__ __launch_bounds__(256) void proj_kernel(
    const float* __restrict__ x, const float* __restrict__ Wi,
    const float* __restrict__ bh, float* __restrict__ out)
{
    __shared__ float xt[64][68];
    __shared__ float wt[64][64];

    const int tid = threadIdx.x;
    const int m0 = blockIdx.x * 64;
    const int j0 = blockIdx.y * 64;
    const int ty = tid >> 4, tx = tid & 15;
    const int r0 = ty * 4;

    float acc[4][4] = {};

#pragma unroll
    for (int half = 0; half < 2; ++half) {
        if (half) __syncthreads();   // protect restage vs previous reads
        {
            const int r  = tid & 63;
            const int kc = tid >> 6;             // 0..3 -> 16 k each
            const float* xsrc = x  + (size_t)(m0 + r) * II + half * 64 + kc * 16;
            const float* wsrc = Wi + (size_t)(j0 + r) * II + half * 64 + kc * 16;
#pragma unroll
            for (int u = 0; u < 4; ++u) {
                float4 v = *(const float4*)(xsrc + u * 4);
                int k = kc * 16 + u * 4;
                xt[k + 0][r] = v.x; xt[k + 1][r] = v.y;
                xt[k + 2][r] = v.z; xt[k + 3][r] = v.w;
            }
#pragma unroll
            for (int u = 0; u < 4; ++u) {
                float4 v = *(const float4*)(wsrc + u * 4);
                int k = kc * 16 + u * 4;
                wt[k + 0][r] = v.x; wt[k + 1][r] = v.y;
                wt[k + 2][r] = v.z; wt[k + 3][r] = v.w;
            }
        }
        __syncthreads();

        const float* xp = &xt[0][r0];
        const float* wp = &wt[0][tx * 4];
#pragma unroll
        for (int kk = 0; kk < 64; kk += 8) {
            float4 av[8], bv[8];
#pragma unroll
            for (int u = 0; u < 8; ++u) {
                av[u] = *(const float4*)(xp + (size_t)(kk + u) * 68);
                bv[u] = *(const float4*)(wp + (size_t)(kk + u) * 64);
            }
#pragma unroll
            for (int u = 0; u < 8; ++u) {
                float a4[4] = {av[u].x, av[u].y, av[u].z, av[u].w};
                float b4[4] = {bv[u].x, bv[u].y, bv[u].z, bv[u].w};
#pragma unroll
                for (int i = 0; i < 4; ++i)
#pragma unroll
                    for (int j = 0; j < 4; ++j)
                        acc[i][j] += a4[i] * b4[j];
            }
        }
    }

    float4 bias = *(const float4*)(bh + j0 + tx * 4);
    float bvv[4] = {bias.x, bias.y, bias.z, bias.w};
#pragma unroll
    for (int i = 0; i < 4; ++i) {
        float4 o;
        o.x = (acc[i][0] + bvv[0]) * TANH_S;
        o.y = (acc[i][1] + bvv[1]) * TANH_S;
        o.z = (acc[i][2] + bvv[2]) * TANH_S;
        o.w = (acc[i][3] + bvv[3]) * TANH_S;
        *(float4*)(out + (size_t)(m0 + r0 + i) * HH + j0 + tx * 4) = o;
    }
}

// ---------------------------------------------------------------------------
// Kernel 2: recurrence — r10 VERBATIM (measured 298us rec, 0 bank conflicts,
// passed).  8 waves was the best operating point: r13's 16-wave variant
// replicated the ~60cyc/wave reduce tail across 2x the waves (+240cyc/SIMD
// issue) and lost more than the latency it hid (355us).
//   512 threads, 1 block/batch row. Wave q owns cols [32q,+32).
//   Lane: kg=(l&3)|((l>>1)&4), cg from bits 2,4,5. Thread = 4 cols x 32 k.
//   Wh frag (PRE-SCALED by 2log2e) in v72-v199 (asm-pinned).
//   h LDS: kg-group padded to 144B, double-buffered (+0x800), 1 barrier/step.
//   Butterfly xor1/xor2/xor8 (12 DPP, all >=3-instr producer gaps) -> late
//   select (3 cndmask) -> +xi -> tanh = 1 - 2*rcp(exp2(arg)+1).
//   ds_write exec-masked to kg<4; global store unmasked (dup addrs merge).
//   xi prefetched one step ahead (vmcnt(2) counted wait).
// ---------------------------------------------------------------------------

#define RNN_CHUNK(CNT, A0,A1,B0,B1,C0,C1,D0,D1, H0,H1) \
        "s_waitcnt lgkmcnt(" CNT ")\n" \
        "v_pk_fma_f32 v[32:33], v[" A0 "], v[" H0 "], v[32:33]\n" \
        "v_pk_fma_f32 v[34:35], v[" B0 "], v[" H0 "], v[34:35]\n" \
        "v_pk_fma_f32 v[36:37], v[" C0 "], v[" H0 "], v[36:37]\n" \
        "v_pk_fma_f32 v[38:39], v[" D0 "], v[" H0 "], v[38:39]\n" \
        "v_pk_fma_f32 v[32:33], v[" A1 "], v[" H1 "], v[32:33]\n" \
        "v_pk_fma_f32 v[34:35], v[" B1 "], v[" H1 "], v[34:35]\n" \
        "v_pk_fma_f32 v[36:37], v[" C1 "], v[" H1 "], v[36:37]\n" \
        "v_pk_fma_f32 v[38:39], v[" D1 "], v[" H1 "], v[38:39]\n"

#define RNN_BODY(XN, XC) \
        /* hv: 8 broadcast b128 (padded, conflict-free) */ \
        "ds_read_b128 v[40:43], v16\n" \
        "ds_read_b128 v[44:47], v16 offset:16\n" \
        "ds_read_b128 v[48:51], v16 offset:32\n" \
        "ds_read_b128 v[52:55], v16 offset:48\n" \
        "ds_read_b128 v[56:59], v16 offset:64\n" \
        "ds_read_b128 v[60:63], v16 offset:80\n" \
        "ds_read_b128 v[64:67], v16 offset:96\n" \
        "ds_read_b128 v[68:71], v16 offset:112\n" \
        /* shadow work while first read lands */ \
        "v_xor_b32 v16, 0x800, v16\n" \
        "global_load_dword " XN ", v18, %[iob]\n" \
        "v_add_u32 v18, 0x40000, v18\n" \
        "v_min_u32 v18, %[viomax], v18\n" \
        /* chunk 0 (quad 0): pk_mul init */ \
        "s_waitcnt lgkmcnt(7)\n" \
        "v_pk_mul_f32 v[32:33], v[72:73],   v[40:41]\n" \
        "v_pk_mul_f32 v[34:35], v[104:105], v[40:41]\n" \
        "v_pk_mul_f32 v[36:37], v[136:137], v[40:41]\n" \
        "v_pk_mul_f32 v[38:39], v[168:169], v[40:41]\n" \
        "v_pk_fma_f32 v[32:33], v[74:75],   v[42:43], v[32:33]\n" \
        "v_pk_fma_f32 v[34:35], v[106:107], v[42:43], v[34:35]\n" \
        "v_pk_fma_f32 v[36:37], v[138:139], v[42:43], v[36:37]\n" \
        "v_pk_fma_f32 v[38:39], v[170:171], v[42:43], v[38:39]\n" \
        RNN_CHUNK("6","76:77","78:79","108:109","110:111","140:141","142:143","172:173","174:175","44:45","46:47") \
        RNN_CHUNK("5","80:81","82:83","112:113","114:115","144:145","146:147","176:177","178:179","48:49","50:51") \
        RNN_CHUNK("4","84:85","86:87","116:117","118:119","148:149","150:151","180:181","182:183","52:53","54:55") \
        RNN_CHUNK("3","88:89","90:91","120:121","122:123","152:153","154:155","184:185","186:187","56:57","58:59") \
        RNN_CHUNK("2","92:93","94:95","124:125","126:127","156:157","158:159","188:189","190:191","60:61","62:63") \
        RNN_CHUNK("1","96:97","98:99","128:129","130:131","160:161","162:163","192:193","194:195","64:65","66:67") \
        RNN_CHUNK("0","100:101","102:103","132:133","134:135","164:165","166:167","196:197","198:199","68:69","70:71") \
        /* merge pk pairs -> 4 col sums */ \
        "v_add_f32 v26, v32, v33\n" \
        "v_add_f32 v27, v34, v35\n" \
        "v_add_f32 v28, v36, v37\n" \
        "v_add_f32 v29, v38, v39\n" \
        /* butterfly over kg: xor1, xor2, xor8 */ \
        "v_add_f32 v26, v26, v26 quad_perm:[1,0,3,2] row_mask:0xf bank_mask:0xf\n" \
        "v_add_f32 v27, v27, v27 quad_perm:[1,0,3,2] row_mask:0xf bank_mask:0xf\n" \
        "v_add_f32 v28, v28, v28 quad_perm:[1,0,3,2] row_mask:0xf bank_mask:0xf\n" \
        "v_add_f32 v29, v29, v29 quad_perm:[1,0,3,2] row_mask:0xf bank_mask:0xf\n" \
        "v_add_f32 v26, v26, v26 quad_perm:[2,3,0,1] row_mask:0xf bank_mask:0xf\n" \
        "v_add_f32 v27, v27, v27 quad_perm:[2,3,0,1] row_mask:0xf bank_mask:0xf\n" \
        "v_add_f32 v28, v28, v28 quad_perm:[2,3,0,1] row_mask:0xf bank_mask:0xf\n" \
        "v_add_f32 v29, v29, v29 quad_perm:[2,3,0,1] row_mask:0xf bank_mask:0xf\n" \
        "v_add_f32 v26, v26, v26 row_ror:8 row_mask:0xf bank_mask:0xf\n" \
        "v_add_f32 v27, v27, v27 row_ror:8 row_mask:0xf bank_mask:0xf\n" \
        "v_add_f32 v28, v28, v28 row_ror:8 row_mask:0xf bank_mask:0xf\n" \
        "v_add_f32 v29, v29, v29 row_ror:8 row_mask:0xf bank_mask:0xf\n" \
        /* select this lane's column (kg&3) */ \
        "v_cndmask_b32 v30, v26, v27, %[m0]\n" \
        "v_cndmask_b32 v31, v28, v29, %[m0]\n" \
        "v_cndmask_b32 v30, v30, v31, %[m1]\n" \
        /* xi (pre-scaled, prefetched last step) */ \
        "s_waitcnt vmcnt(2)\n" \
        "v_add_f32 v30, v30, " XC "\n" \
        /* tanh = 1 - 2*rcp(exp2(arg)+1); arg already scaled by 2log2e */ \
        "v_exp_f32 v19, v30\n" \
        "s_nop 0\n" \
        "v_add_f32 v19, 1.0, v19\n" \
        "v_rcp_f32 v19, v19\n" \
        "s_nop 0\n" \
        "v_fma_f32 v30, -2.0, v19, 1.0\n" \
        /* masked LDS h write (kg<4 lanes only) */ \
        "s_and_saveexec_b64 s[84:85], %[msk]\n" \
        "ds_write_b32 v17, v30\n" \
        "s_mov_b64 exec, s[84:85]\n" \
        "v_xor_b32 v17, 0x800, v17\n" \
        /* global h store: all lanes, dup addrs merge */ \
        "global_store_dword v23, v30, %[iob]\n" \
        "v_add_u32 v23, 0x40000, v23\n" \
        "s_waitcnt lgkmcnt(0)\n" \
        "s_barrier\n"

#define SCALE_PAIR(P) "v_pk_mul_f32 v[" P "], v[" P "], v[26:27]\n"

__global__ __launch_bounds__(512, 2) void rec_kernel(
    const float* __restrict__ Wh, const float* __restrict__ h0,
    float* __restrict__ io)
{
    __shared__ float hbuf[864];  // buf0 [0,1152) buf1 [0x800,+1152)

    const int tid  = threadIdx.x;
    const int b    = blockIdx.x;
    const int lane = tid & 63;
    const int q    = tid >> 6;                       // wave id 0..7
    const int kg   = (lane & 3) | ((lane >> 1) & 4); // 0..7
    const int cg   = ((lane >> 2) & 1) | ((lane >> 3) & 6); // 0..7
    const int col0 = 32 * q + 4 * cg;
    const int col  = col0 + (kg & 3);                // finalize column

    const float* wp  = Wh + (size_t)col0 * HH + kg * 32;
    const float* iob = io + (size_t)b * HH;
    unsigned hbase = (unsigned)(size_t)&hbuf[0];
    unsigned hvr = hbase + kg * 144;                 // read base (buf0)
    unsigned hvw = hbase + 0x800 + q * 144 + (4 * cg + (kg & 3)) * 4;
    unsigned vio = (unsigned)(col * 4);
    unsigned viomax = vio + 511u * 0x40000u;         // last valid xi plane
    unsigned long long m0 = __ballot((lane & 1) != 0);
    unsigned long long m1 = __ballot((lane & 2) != 0);
    unsigned long long msk = __ballot(kg < 4);       // LDS-writer lanes

    if (tid < HH) hbuf[(tid >> 5) * 36 + (tid & 31)] = h0[(size_t)b * HH + tid];
    __syncthreads();

    asm volatile(
        // ---- Wh fragment: w[j][m] -> v[72+32j+4m] ----
        "global_load_dwordx4 v[72:75],   %[wp], off\n"
        "global_load_dwordx4 v[76:79],   %[wp], off offset:16\n"
        "global_load_dwordx4 v[80:83],   %[wp], off offset:32\n"
        "global_load_dwordx4 v[84:87],   %[wp], off offset:48\n"
        "global_load_dwordx4 v[88:91],   %[wp], off offset:64\n"
        "global_load_dwordx4 v[92:95],   %[wp], off offset:80\n"
        "global_load_dwordx4 v[96:99],   %[wp], off offset:96\n"
        "global_load_dwordx4 v[100:103], %[wp], off offset:112\n"
        "global_load_dwordx4 v[104:107], %[wp], off offset:1024\n"
        "global_load_dwordx4 v[108:111], %[wp], off offset:1040\n"
        "global_load_dwordx4 v[112:115], %[wp], off offset:1056\n"
        "global_load_dwordx4 v[116:119], %[wp], off offset:1072\n"
        "global_load_dwordx4 v[120:123], %[wp], off offset:1088\n"
        "global_load_dwordx4 v[124:127], %[wp], off offset:1104\n"
        "global_load_dwordx4 v[128:131], %[wp], off offset:1120\n"
        "global_load_dwordx4 v[132:135], %[wp], off offset:1136\n"
        "global_load_dwordx4 v[136:139], %[wp], off offset:2048\n"
        "global_load_dwordx4 v[140:143], %[wp], off offset:2064\n"
        "global_load_dwordx4 v[144:147], %[wp], off offset:2080\n"
        "global_load_dwordx4 v[148:151], %[wp], off offset:2096\n"
        "global_load_dwordx4 v[152:155], %[wp], off offset:2112\n"
        "global_load_dwordx4 v[156:159], %[wp], off offset:2128\n"
        "global_load_dwordx4 v[160:163], %[wp], off offset:2144\n"
        "global_load_dwordx4 v[164:167], %[wp], off offset:2160\n"
        "global_load_dwordx4 v[168:171], %[wp], off offset:3072\n"
        "global_load_dwordx4 v[172:175], %[wp], off offset:3088\n"
        "global_load_dwordx4 v[176:179], %[wp], off offset:3104\n"
        "global_load_dwordx4 v[180:183], %[wp], off offset:3120\n"
        "global_load_dwordx4 v[184:187], %[wp], off offset:3136\n"
        "global_load_dwordx4 v[188:191], %[wp], off offset:3152\n"
        "global_load_dwordx4 v[192:195], %[wp], off offset:3168\n"
        "global_load_dwordx4 v[196:199], %[wp], off offset:3184\n"
        // ---- init + xi_0 prologue load ----
        "v_mov_b32 v16, %[hvr]\n"
        "v_mov_b32 v17, %[hvw]\n"
        "v_mov_b32 v18, %[vio]\n"
        "v_mov_b32 v23, %[vio]\n"
        "global_load_dword v21, v18, %[iob]\n"
        "v_add_u32 v18, 0x40000, v18\n"
        "s_movk_i32 s82, 0x100\n"
        "s_waitcnt vmcnt(0)\n"
        // ---- one-time pre-scale of Wh fragment by 2*log2(e) ----
        "v_mov_b32 v26, 0x4038aa3b\n"
        "v_mov_b32 v27, 0x4038aa3b\n"
        SCALE_PAIR("72:73")   SCALE_PAIR("74:75")   SCALE_PAIR("76:77")   SCALE_PAIR("78:79")
        SCALE_PAIR("80:81")   SCALE_PAIR("82:83")   SCALE_PAIR("84:85")   SCALE_PAIR("86:87")
        SCALE_PAIR("88:89")   SCALE_PAIR("90:91")   SCALE_PAIR("92:93")   SCALE_PAIR("94:95")
        SCALE_PAIR("96:97")   SCALE_PAIR("98:99")   SCALE_PAIR("100:101") SCALE_PAIR("102:103")
        SCALE_PAIR("104:105") SCALE_PAIR("106:107") SCALE_PAIR("108:109") SCALE_PAIR("110:111")
        SCALE_PAIR("112:113") SCALE_PAIR("114:115") SCALE_PAIR("116:117") SCALE_PAIR("118:119")
        SCALE_PAIR("120:121") SCALE_PAIR("122:123") SCALE_PAIR("124:125") SCALE_PAIR("126:127")
        SCALE_PAIR("128:129") SCALE_PAIR("130:131") SCALE_PAIR("132:133") SCALE_PAIR("134:135")
        SCALE_PAIR("136:137") SCALE_PAIR("138:139") SCALE_PAIR("140:141") SCALE_PAIR("142:143")
        SCALE_PAIR("144:145") SCALE_PAIR("146:147") SCALE_PAIR("148:149") SCALE_PAIR("150:151")
        SCALE_PAIR("152:153") SCALE_PAIR("154:155") SCALE_PAIR("156:157") SCALE_PAIR("158:159")
        SCALE_PAIR("160:161") SCALE_PAIR("162:163") SCALE_PAIR("164:165") SCALE_PAIR("166:167")
        SCALE_PAIR("168:169") SCALE_PAIR("170:171") SCALE_PAIR("172:173") SCALE_PAIR("174:175")
        SCALE_PAIR("176:177") SCALE_PAIR("178:179") SCALE_PAIR("180:181") SCALE_PAIR("182:183")
        SCALE_PAIR("184:185") SCALE_PAIR("186:187") SCALE_PAIR("188:189") SCALE_PAIR("190:191")
        SCALE_PAIR("192:193") SCALE_PAIR("194:195") SCALE_PAIR("196:197") SCALE_PAIR("198:199")
        "LTOP_%=:\n"
        RNN_BODY("v20", "v21")
        RNN_BODY("v21", "v20")
        "s_sub_u32 s82, s82, 1\n"
        "s_cmp_lg_u32 s82, 0\n"
        "s_cbranch_scc1 LTOP_%=\n"
        :
        : [wp] "v"(wp), [iob] "s"(iob),
          [hvr] "v"(hvr), [hvw] "v"(hvw), [vio] "v"(vio),
          [viomax] "v"(viomax), [m0] "s"(m0), [m1] "s"(m1), [msk] "s"(msk)
        : "memory", "scc", "s82", "s84", "s85",
          "v16","v17","v18","v19","v20","v21","v22","v23",
          "v24","v25","v26","v27","v28","v29","v30","v31",
          "v32","v33","v34","v35","v36","v37","v38","v39",
          "v40","v41","v42","v43","v44","v45","v46","v47",
          "v48","v49","v50","v51","v52","v53","v54","v55",
          "v56","v57","v58","v59","v60","v61","v62","v63",
          "v64","v65","v66","v67","v68","v69","v70","v71",
          "v72","v73","v74","v75","v76","v77","v78","v79",
          "v80","v81","v82","v83","v84","v85","v86","v87",
          "v88","v89","v90","v91","v92","v93","v94","v95",
          "v96","v97","v98","v99","v100","v101","v102","v103",
          "v104","v105","v106","v107","v108","v109","v110","v111",
          "v112","v113","v114","v115","v116","v117","v118","v119",
          "v120","v121","v122","v123","v124","v125","v126","v127",
          "v128","v129","v130","v131","v132","v133","v134","v135",
          "v136","v137","v138","v139","v140","v141","v142","v143",
          "v144","v145","v146","v147","v148","v149","v150","v151",
          "v152","v153","v154","v155","v156","v157","v158","v159",
          "v160","v161","v162","v163","v164","v165","v166","v167",
          "v168","v169","v170","v171","v172","v173","v174","v175",
          "v176","v177","v178","v179","v180","v181","v182","v183",
          "v184","v185","v186","v187","v188","v189","v190","v191",
          "v192","v193","v194","v195","v196","v197","v198","v199");
}

extern "C" void kernel_launch(void* const* d_in, const int* in_sizes, int n_in,
                              void* d_out, int out_size, void* d_ws, size_t ws_size,
                              hipStream_t stream) {
    const float* x  = (const float*)d_in[0];  // [T,B,I]
    const float* h0 = (const float*)d_in[1];  // [B,H]
    const float* Wi = (const float*)d_in[2];  // [H,I]
    const float* Wh = (const float*)d_in[3];  // [H,H]
    const float* bh = (const float*)d_in[4];  // [H]
    float* out = (float*)d_out;               // [T,B,H]

    dim3 pgrid(TT * BB / 64, HH / 64);
    proj_kernel<<<pgrid, 256, 0, stream>>>(x, Wi, bh, out);
    rec_kernel<<<BB, 512, 0, stream>>>(Wh, h0, out);
}

// Round 15
// 343.351 us; speedup vs baseline: 1.2667x; 1.1420x over previous
//
#include <hip/hip_runtime.h>
#include <hip/hip_bf16.h>
#include <math.h>

// Problem dims (fixed): T=512, B=256, I=128, H=256
#define TT 512
#define BB 256
#define II 128
#define HH 256

// 2*log2(e): Wh, Wi, bh pre-scaled so tanh is exp2-direct.
#define TANH_S 2.885390043258667f

// ---------------------------------------------------------------------------
// Single fused kernel: h_t = tanh(Wh·h_{t-1} + Wi·x_t + bh), out[t] = h_t.
// The input projection (was a separate 80-94us proj_kernel) is fused as an
// augmented-K dot: [Wh | Wi]·[h ; x].  512 threads = 8 waves, 1 block/row.
//
// Decomposition (r10-proven skeleton): wave q owns cols [32q,+32).
//   Lane: kg=(l&3)|((l>>1)&4) (8 k-groups), cg = bits 2,4,5 (8 col-quads).
//   Thread = 4 cols x (32 Wh-k + 16 Wi-k).
// Registers (exactly 256 = 2 waves/SIMD, pool 512/SIMD):
//   v0-15 compiler | v16 hv-read base | v17 h-write | v18 x-load ofs |
//   v19 bh*S | v20-23 x stage | v24 x-write | v25 h-store ofs |
//   v26-31 butterfly/select/tanh | v32-39 acc | v40-63 6 rotating quad slots|
//   v64-191 Wh frag | v192-255 Wi frag.
// LDS: per buffer 8 groups x 208B (h 32f @0 + x 16f @128; 208B stride ->
//   8 group bases on 8 distinct bank quads -> broadcast b128 conflict-free).
//   Double-buffered at +0x800, ONE barrier/step.
// x_{t+1}: 32 masked lanes global f4 load at step top -> vmcnt(1) + b128
//   LDS write in tail (issue-early/write-late; hides ~900cyc HBM latency).
// FMA: 12 quads through 6 slots, counted lgkm waits 5,5,5,5,5,5,5,4,3,2,1,0.
// Tail: merge -> 12-DPP butterfly (r10 hazard-safe ordering) -> select ->
//   +bh*S -> exp2/rcp tanh -> masked h LDS write + global store.
// ---------------------------------------------------------------------------

#define FCHUNK(CNT, A0,A1,B0,B1,C0,C1,D0,D1, H0,H1) \
        "s_waitcnt lgkmcnt(" CNT ")\n" \
        "v_pk_fma_f32 v[32:33], v[" A0 "], v[" H0 "], v[32:33]\n" \
        "v_pk_fma_f32 v[34:35], v[" B0 "], v[" H0 "], v[34:35]\n" \
        "v_pk_fma_f32 v[36:37], v[" C0 "], v[" H0 "], v[36:37]\n" \
        "v_pk_fma_f32 v[38:39], v[" D0 "], v[" H0 "], v[38:39]\n" \
        "v_pk_fma_f32 v[32:33], v[" A1 "], v[" H1 "], v[32:33]\n" \
        "v_pk_fma_f32 v[34:35], v[" B1 "], v[" H1 "], v[34:35]\n" \
        "v_pk_fma_f32 v[36:37], v[" C1 "], v[" H1 "], v[36:37]\n" \
        "v_pk_fma_f32 v[38:39], v[" D1 "], v[" H1 "], v[38:39]\n"

#define SCALE_PAIR(P) "v_pk_mul_f32 v[" P "], v[" P "], v[26:27]\n"

__global__ __launch_bounds__(512, 2) void rnn_fused_kernel(
    const float* __restrict__ x,  const float* __restrict__ h0,
    const float* __restrict__ Wi, const float* __restrict__ Wh,
    const float* __restrict__ bh, float* __restrict__ out)
{
    __shared__ float hbuf[928];  // buf0 [0,1664B) buf1 [0x800,+1664B)

    const int tid  = threadIdx.x;
    const int b    = blockIdx.x;
    const int lane = tid & 63;
    const int q    = tid >> 6;                       // wave id 0..7
    const int kg   = (lane & 3) | ((lane >> 1) & 4); // 0..7
    const int cg   = ((lane >> 2) & 1) | ((lane >> 3) & 6); // 0..7
    const int col0 = 32 * q + 4 * cg;
    const int col  = col0 + (kg & 3);                // finalize column

    const float* wp  = Wh + (size_t)col0 * HH + kg * 32;  // Wh frag base
    const float* wip = Wi + (size_t)col0 * II + kg * 16;  // Wi frag base
    const float* iob = out + (size_t)b * HH;              // h store base
    const float* xb  = x   + (size_t)b * II;              // x load base
    unsigned hbase = (unsigned)(size_t)&hbuf[0];
    unsigned hvr = hbase + kg * 208;                      // read base (buf0)
    unsigned hvw = hbase + 0x800 + q * 208 + (4 * cg + (kg & 3)) * 4;
    unsigned vxw = hbase + 0x800 + (tid >> 2) * 208 + 128 + 16 * (tid & 3);
    unsigned vxo = (unsigned)(16 * tid) + 0x20000u;       // x plane 1
    unsigned vxomax = (unsigned)(16 * tid) + 511u * 0x20000u;
    unsigned vho = (unsigned)(col * 4);                   // h store ofs
    float bhv = bh[col] * TANH_S;
    unsigned long long m0   = __ballot((lane & 1) != 0);
    unsigned long long m1   = __ballot((lane & 2) != 0);
    unsigned long long msk  = __ballot(kg < 4);           // h LDS writers
    unsigned long long mskx = __ballot(tid < 32);         // x stagers

    // stage h0 + x0 into buffer 0 (group-interleaved layout)
    if (tid < HH) hbuf[(tid >> 5) * 52 + (tid & 31)] = h0[(size_t)b * HH + tid];
    if (tid < II) hbuf[(tid >> 4) * 52 + 32 + (tid & 15)] = xb[tid];
    __syncthreads();

    asm volatile(
        // ---- Wh fragment: col j quad m -> v[64+32j+4m] ----
        "global_load_dwordx4 v[64:67],   %[wp], off\n"
        "global_load_dwordx4 v[68:71],   %[wp], off offset:16\n"
        "global_load_dwordx4 v[72:75],   %[wp], off offset:32\n"
        "global_load_dwordx4 v[76:79],   %[wp], off offset:48\n"
        "global_load_dwordx4 v[80:83],   %[wp], off offset:64\n"
        "global_load_dwordx4 v[84:87],   %[wp], off offset:80\n"
        "global_load_dwordx4 v[88:91],   %[wp], off offset:96\n"
        "global_load_dwordx4 v[92:95],   %[wp], off offset:112\n"
        "global_load_dwordx4 v[96:99],   %[wp], off offset:1024\n"
        "global_load_dwordx4 v[100:103], %[wp], off offset:1040\n"
        "global_load_dwordx4 v[104:107], %[wp], off offset:1056\n"
        "global_load_dwordx4 v[108:111], %[wp], off offset:1072\n"
        "global_load_dwordx4 v[112:115], %[wp], off offset:1088\n"
        "global_load_dwordx4 v[116:119], %[wp], off offset:1104\n"
        "global_load_dwordx4 v[120:123], %[wp], off offset:1120\n"
        "global_load_dwordx4 v[124:127], %[wp], off offset:1136\n"
        "global_load_dwordx4 v[128:131], %[wp], off offset:2048\n"
        "global_load_dwordx4 v[132:135], %[wp], off offset:2064\n"
        "global_load_dwordx4 v[136:139], %[wp], off offset:2080\n"
        "global_load_dwordx4 v[140:143], %[wp], off offset:2096\n"
        "global_load_dwordx4 v[144:147], %[wp], off offset:2112\n"
        "global_load_dwordx4 v[148:151], %[wp], off offset:2128\n"
        "global_load_dwordx4 v[152:155], %[wp], off offset:2144\n"
        "global_load_dwordx4 v[156:159], %[wp], off offset:2160\n"
        "global_load_dwordx4 v[160:163], %[wp], off offset:3072\n"
        "global_load_dwordx4 v[164:167], %[wp], off offset:3088\n"
        "global_load_dwordx4 v[168:171], %[wp], off offset:3104\n"
        "global_load_dwordx4 v[172:175], %[wp], off offset:3120\n"
        "global_load_dwordx4 v[176:179], %[wp], off offset:3136\n"
        "global_load_dwordx4 v[180:183], %[wp], off offset:3152\n"
        "global_load_dwordx4 v[184:187], %[wp], off offset:3168\n"
        "global_load_dwordx4 v[188:191], %[wp], off offset:3184\n"
        // ---- Wi fragment: col j quad n -> v[192+16j+4n] ----
        "global_load_dwordx4 v[192:195], %[wip], off\n"
        "global_load_dwordx4 v[196:199], %[wip], off offset:16\n"
        "global_load_dwordx4 v[200:203], %[wip], off offset:32\n"
        "global_load_dwordx4 v[204:207], %[wip], off offset:48\n"
        "global_load_dwordx4 v[208:211], %[wip], off offset:512\n"
        "global_load_dwordx4 v[212:215], %[wip], off offset:528\n"
        "global_load_dwordx4 v[216:219], %[wip], off offset:544\n"
        "global_load_dwordx4 v[220:223], %[wip], off offset:560\n"
        "global_load_dwordx4 v[224:227], %[wip], off offset:1024\n"
        "global_load_dwordx4 v[228:231], %[wip], off offset:1040\n"
        "global_load_dwordx4 v[232:235], %[wip], off offset:1056\n"
        "global_load_dwordx4 v[236:239], %[wip], off offset:1072\n"
        "global_load_dwordx4 v[240:243], %[wip], off offset:1536\n"
        "global_load_dwordx4 v[244:247], %[wip], off offset:1552\n"
        "global_load_dwordx4 v[248:251], %[wip], off offset:1568\n"
        "global_load_dwordx4 v[252:255], %[wip], off offset:1584\n"
        // ---- init ----
        "v_mov_b32 v16, %[hvr]\n"
        "v_mov_b32 v17, %[hvw]\n"
        "v_mov_b32 v18, %[vxo]\n"
        "v_mov_b32 v19, %[bhv]\n"
        "v_mov_b32 v24, %[vxw]\n"
        "v_mov_b32 v25, %[vho]\n"
        "s_movk_i32 s82, 0x200\n"
        "s_waitcnt vmcnt(0)\n"
        // ---- one-time pre-scale of Wh+Wi fragments by 2*log2(e) ----
        "v_mov_b32 v26, 0x4038aa3b\n"
        "v_mov_b32 v27, 0x4038aa3b\n"
        SCALE_PAIR("64:65")   SCALE_PAIR("66:67")   SCALE_PAIR("68:69")   SCALE_PAIR("70:71")
        SCALE_PAIR("72:73")   SCALE_PAIR("74:75")   SCALE_PAIR("76:77")   SCALE_PAIR("78:79")
        SCALE_PAIR("80:81")   SCALE_PAIR("82:83")   SCALE_PAIR("84:85")   SCALE_PAIR("86:87")
        SCALE_PAIR("88:89")   SCALE_PAIR("90:91")   SCALE_PAIR("92:93")   SCALE_PAIR("94:95")
        SCALE_PAIR("96:97")   SCALE_PAIR("98:99")   SCALE_PAIR("100:101") SCALE_PAIR("102:103")
        SCALE_PAIR("104:105") SCALE_PAIR("106:107") SCALE_PAIR("108:109") SCALE_PAIR("110:111")
        SCALE_PAIR("112:113") SCALE_PAIR("114:115") SCALE_PAIR("116:117") SCALE_PAIR("118:119")
        SCALE_PAIR("120:121") SCALE_PAIR("122:123") SCALE_PAIR("124:125") SCALE_PAIR("126:127")
        SCALE_PAIR("128:129") SCALE_PAIR("130:131") SCALE_PAIR("132:133") SCALE_PAIR("134:135")
        SCALE_PAIR("136:137") SCALE_PAIR("138:139") SCALE_PAIR("140:141") SCALE_PAIR("142:143")
        SCALE_PAIR("144:145") SCALE_PAIR("146:147") SCALE_PAIR("148:149") SCALE_PAIR("150:151")
        SCALE_PAIR("152:153") SCALE_PAIR("154:155") SCALE_PAIR("156:157") SCALE_PAIR("158:159")
        SCALE_PAIR("160:161") SCALE_PAIR("162:163") SCALE_PAIR("164:165") SCALE_PAIR("166:167")
        SCALE_PAIR("168:169") SCALE_PAIR("170:171") SCALE_PAIR("172:173") SCALE_PAIR("174:175")
        SCALE_PAIR("176:177") SCALE_PAIR("178:179") SCALE_PAIR("180:181") SCALE_PAIR("182:183")
        SCALE_PAIR("184:185") SCALE_PAIR("186:187") SCALE_PAIR("188:189") SCALE_PAIR("190:191")
        SCALE_PAIR("192:193") SCALE_PAIR("194:195") SCALE_PAIR("196:197") SCALE_PAIR("198:199")
        SCALE_PAIR("200:201") SCALE_PAIR("202:203") SCALE_PAIR("204:205") SCALE_PAIR("206:207")
        SCALE_PAIR("208:209") SCALE_PAIR("210:211") SCALE_PAIR("212:213") SCALE_PAIR("214:215")
        SCALE_PAIR("216:217") SCALE_PAIR("218:219") SCALE_PAIR("220:221") SCALE_PAIR("222:223")
        SCALE_PAIR("224:225") SCALE_PAIR("226:227") SCALE_PAIR("228:229") SCALE_PAIR("230:231")
        SCALE_PAIR("232:233") SCALE_PAIR("234:235") SCALE_PAIR("236:237") SCALE_PAIR("238:239")
        SCALE_PAIR("240:241") SCALE_PAIR("242:243") SCALE_PAIR("244:245") SCALE_PAIR("246:247")
        SCALE_PAIR("248:249") SCALE_PAIR("250:251") SCALE_PAIR("252:253") SCALE_PAIR("254:255")
        "LTOP_%=:\n"
        // ---- x_{t+1} prefetch (32 masked lanes); clamp final plane ----
        "s_and_saveexec_b64 s[86:87], %[mskx]\n"
        "global_load_dwordx4 v[20:23], v18, %[xb]\n"
        "s_mov_b64 exec, s[86:87]\n"
        "v_add_u32 v18, 0x20000, v18\n"
        "v_min_u32 v18, %[vxomax], v18\n"
        // ---- issue 6 quads (h quads 0-5) ----
        "ds_read_b128 v[40:43], v16\n"
        "ds_read_b128 v[44:47], v16 offset:16\n"
        "ds_read_b128 v[48:51], v16 offset:32\n"
        "ds_read_b128 v[52:55], v16 offset:48\n"
        "ds_read_b128 v[56:59], v16 offset:64\n"
        "ds_read_b128 v[60:63], v16 offset:80\n"
        // ---- Wh m=0 (slot 40-43): pk_mul init; reissue slot <- h quad6 ----
        "s_waitcnt lgkmcnt(5)\n"
        "v_pk_mul_f32 v[32:33], v[64:65],   v[40:41]\n"
        "v_pk_mul_f32 v[34:35], v[96:97],   v[40:41]\n"
        "v_pk_mul_f32 v[36:37], v[128:129], v[40:41]\n"
        "v_pk_mul_f32 v[38:39], v[160:161], v[40:41]\n"
        "v_pk_fma_f32 v[32:33], v[66:67],   v[42:43], v[32:33]\n"
        "v_pk_fma_f32 v[34:35], v[98:99],   v[42:43], v[34:35]\n"
        "v_pk_fma_f32 v[36:37], v[130:131], v[42:43], v[36:37]\n"
        "v_pk_fma_f32 v[38:39], v[162:163], v[42:43], v[38:39]\n"
        "ds_read_b128 v[40:43], v16 offset:96\n"
        // ---- Wh m=1 (44-47); reissue <- h quad7 ----
        FCHUNK("5","68:69","70:71","100:101","102:103","132:133","134:135","164:165","166:167","44:45","46:47")
        "ds_read_b128 v[44:47], v16 offset:112\n"
        // ---- Wh m=2 (48-51); reissue <- x quad0 ----
        FCHUNK("5","72:73","74:75","104:105","106:107","136:137","138:139","168:169","170:171","48:49","50:51")
        "ds_read_b128 v[48:51], v16 offset:128\n"
        // ---- Wh m=3 (52-55); reissue <- x quad1 ----
        FCHUNK("5","76:77","78:79","108:109","110:111","140:141","142:143","172:173","174:175","52:53","54:55")
        "ds_read_b128 v[52:55], v16 offset:144\n"
        // ---- Wh m=4 (56-59); reissue <- x quad2 ----
        FCHUNK("5","80:81","82:83","112:113","114:115","144:145","146:147","176:177","178:179","56:57","58:59")
        "ds_read_b128 v[56:59], v16 offset:160\n"
        // ---- Wh m=5 (60-63); reissue <- x quad3 ----
        FCHUNK("5","84:85","86:87","116:117","118:119","148:149","150:151","180:181","182:183","60:61","62:63")
        "ds_read_b128 v[60:63], v16 offset:176\n"
        // ---- Wh m=6 (40-43) ----
        FCHUNK("5","88:89","90:91","120:121","122:123","152:153","154:155","184:185","186:187","40:41","42:43")
        // ---- Wh m=7 (44-47) ----
        FCHUNK("4","92:93","94:95","124:125","126:127","156:157","158:159","188:189","190:191","44:45","46:47")
        // ---- Wi n=0 (48-51) ----
        FCHUNK("3","192:193","194:195","208:209","210:211","224:225","226:227","240:241","242:243","48:49","50:51")
        // ---- Wi n=1 (52-55) ----
        FCHUNK("2","196:197","198:199","212:213","214:215","228:229","230:231","244:245","246:247","52:53","54:55")
        // ---- Wi n=2 (56-59) ----
        FCHUNK("1","200:201","202:203","216:217","218:219","232:233","234:235","248:249","250:251","56:57","58:59")
        // ---- Wi n=3 (60-63) ----
        FCHUNK("0","204:205","206:207","220:221","222:223","236:237","238:239","252:253","254:255","60:61","62:63")
        // ---- merge pk pairs -> 4 col sums ----
        "v_add_f32 v26, v32, v33\n"
        "v_add_f32 v27, v34, v35\n"
        "v_add_f32 v28, v36, v37\n"
        "v_add_f32 v29, v38, v39\n"
        // ---- butterfly over kg: xor1, xor2, xor8 (r10 hazard-safe) ----
        "v_add_f32 v26, v26, v26 quad_perm:[1,0,3,2] row_mask:0xf bank_mask:0xf\n"
        "v_add_f32 v27, v27, v27 quad_perm:[1,0,3,2] row_mask:0xf bank_mask:0xf\n"
        "v_add_f32 v28, v28, v28 quad_perm:[1,0,3,2] row_mask:0xf bank_mask:0xf\n"
        "v_add_f32 v29, v29, v29 quad_perm:[1,0,3,2] row_mask:0xf bank_mask:0xf\n"
        "v_add_f32 v26, v26, v26 quad_perm:[2,3,0,1] row_mask:0xf bank_mask:0xf\n"
        "v_add_f32 v27, v27, v27 quad_perm:[2,3,0,1] row_mask:0xf bank_mask:0xf\n"
        "v_add_f32 v28, v28, v28 quad_perm:[2,3,0,1] row_mask:0xf bank_mask:0xf\n"
        "v_add_f32 v29, v29, v29 quad_perm:[2,3,0,1] row_mask:0xf bank_mask:0xf\n"
        "v_add_f32 v26, v26, v26 row_ror:8 row_mask:0xf bank_mask:0xf\n"
        "v_add_f32 v27, v27, v27 row_ror:8 row_mask:0xf bank_mask:0xf\n"
        "v_add_f32 v28, v28, v28 row_ror:8 row_mask:0xf bank_mask:0xf\n"
        "v_add_f32 v29, v29, v29 row_ror:8 row_mask:0xf bank_mask:0xf\n"
        // ---- select this lane's column (kg&3) ----
        "v_cndmask_b32 v30, v26, v27, %[m0]\n"
        "v_cndmask_b32 v31, v28, v29, %[m0]\n"
        "v_cndmask_b32 v30, v30, v31, %[m1]\n"
        // ---- + bh*S ; tanh = 1 - 2*rcp(exp2(arg)+1) ----
        "v_add_f32 v30, v30, v19\n"
        "v_exp_f32 v31, v30\n"
        "s_nop 0\n"
        "v_add_f32 v31, 1.0, v31\n"
        "v_rcp_f32 v31, v31\n"
        "s_nop 0\n"
        "v_fma_f32 v30, -2.0, v31, 1.0\n"
        // ---- masked LDS h write (kg<4) ----
        "s_and_saveexec_b64 s[84:85], %[msk]\n"
        "ds_write_b32 v17, v30\n"
        "s_mov_b64 exec, s[84:85]\n"
        "v_xor_b32 v17, 0x800, v17\n"
        // ---- global h store (all lanes; dup addrs merge) ----
        "global_store_dword v25, v30, %[iob]\n"
        "v_add_u32 v25, 0x40000, v25\n"
        // ---- x stage write: wait x load (leave newest=h-store in flight) ----
        "s_waitcnt vmcnt(1)\n"
        "s_and_saveexec_b64 s[86:87], %[mskx]\n"
        "ds_write_b128 v24, v[20:23]\n"
        "s_mov_b64 exec, s[86:87]\n"
        "v_xor_b32 v24, 0x800, v24\n"
        "s_waitcnt lgkmcnt(0)\n"
        "s_barrier\n"
        "v_xor_b32 v16, 0x800, v16\n"
        // ---- loop ----
        "s_sub_u32 s82, s82, 1\n"
        "s_cmp_lg_u32 s82, 0\n"
        "s_cbranch_scc1 LTOP_%=\n"
        :
        : [wp] "v"(wp), [wip] "v"(wip), [iob] "s"(iob), [xb] "s"(xb),
          [hvr] "v"(hvr), [hvw] "v"(hvw), [vxo] "v"(vxo),
          [vxomax] "v"(vxomax), [vxw] "v"(vxw), [vho] "v"(vho),
          [bhv] "v"(bhv),
          [m0] "s"(m0), [m1] "s"(m1), [msk] "s"(msk), [mskx] "s"(mskx)
        : "memory", "scc", "s82", "s84", "s85", "s86", "s87",
          "v16","v17","v18","v19","v20","v21","v22","v23",
          "v24","v25","v26","v27","v28","v29","v30","v31",
          "v32","v33","v34","v35","v36","v37","v38","v39",
          "v40","v41","v42","v43","v44","v45","v46","v47",
          "v48","v49","v50","v51","v52","v53","v54","v55",
          "v56","v57","v58","v59","v60","v61","v62","v63",
          "v64","v65","v66","v67","v68","v69","v70","v71",
          "v72","v73","v74","v75","v76","v77","v78","v79",
          "v80","v81","v82","v83","v84","v85","v86","v87",
          "v88","v89","v90","v91","v92","v93","v94","v95",
          "v96","v97","v98","v99","v100","v101","v102","v103",
          "v104","v105","v106","v107","v108","v109","v110","v111",
          "v112","v113","v114","v115","v116","v117","v118","v119",
          "v120","v121","v122","v123","v124","v125","v126","v127",
          "v128","v129","v130","v131","v132","v133","v134","v135",
          "v136","v137","v138","v139","v140","v141","v142","v143",
          "v144","v145","v146","v147","v148","v149","v150","v151",
          "v152","v153","v154","v155","v156","v157","v158","v159",
          "v160","v161","v162","v163","v164","v165","v166","v167",
          "v168","v169","v170","v171","v172","v173","v174","v175",
          "v176","v177","v178","v179","v180","v181","v182","v183",
          "v184","v185","v186","v187","v188","v189","v190","v191",
          "v192","v193","v194","v195","v196","v197","v198","v199",
          "v200","v201","v202","v203","v204","v205","v206","v207",
          "v208","v209","v210","v211","v212","v213","v214","v215",
          "v216","v217","v218","v219","v220","v221","v222","v223",
          "v224","v225","v226","v227","v228","v229","v230","v231",
          "v232","v233","v234","v235","v236","v237","v238","v239",
          "v240","v241","v242","v243","v244","v245","v246","v247",
          "v248","v249","v250","v251","v252","v253","v254","v255");
}

extern "C" void kernel_launch(void* const* d_in, const int* in_sizes, int n_in,
                              void* d_out, int out_size, void* d_ws, size_t ws_size,
                              hipStream_t stream) {
    const float* x  = (const float*)d_in[0];  // [T,B,I]
    const float* h0 = (const float*)d_in[1];  // [B,H]
    const float* Wi = (const float*)d_in[2];  // [H,I]
    const float* Wh = (const float*)d_in[3];  // [H,H]
    const float* bh = (const float*)d_in[4];  // [H]
    float* out = (float*)d_out;               // [T,B,H]

    rnn_fused_kernel<<<BB, 512, 0, stream>>>(x, h0, Wi, Wh, bh, out);
}

// Round 16
// 337.410 us; speedup vs baseline: 1.2890x; 1.0176x over previous
//
#include <hip/hip_runtime.h>
#include <hip/hip_bf16.h>
#include <math.h>

// Problem dims (fixed): T=512, B=256, I=128, H=256
#define TT 512
#define BB 256
#define II 128
#define HH 256

// 2*log2(e): Wh, Wi, bh pre-scaled so tanh is exp2-direct.
#define TANH_S 2.885390043258667f

// ---------------------------------------------------------------------------
// Single fused kernel: h_t = tanh(Wh·h_{t-1} + Wi·x_t + bh), out[t] = h_t.
// r15 structure (fused augmented-K dot, 512 thr = 8 waves, 1 block/row,
// one barrier/step) + TWO-step-ahead x prefetch:
//   r15's x window (load at step top -> vmcnt wait at same step's tail) was
//   ~one FMA phase (~800-1000cyc) vs ~900-1100cyc HBM latency -> wave 0
//   stalled at the x-write and delayed every barrier. Now x_{t+2} is loaded
//   at step t top and consumed at step t+1's write (window ~2 steps).
// Register changes vs r15: tail merge/butterfly retargeted to the dead acc
//   regs (v32/34/36/38; select into v30/v31) -> v26-29 freed = 2nd x set.
//   x sets ping-pong (v20-23 / v26-29) via 2-body unroll; steady-state wait
//   vmcnt(2); first two bodies PEELED (step 0 uses vmcnt(0)) so the count
//   is exact. x LDS-write moved right after the FMA chunks (retires under
//   the tail). DPP producer gaps re-verified >=2 everywhere.
// ---------------------------------------------------------------------------

#define FCHUNK(CNT, A0,A1,B0,B1,C0,C1,D0,D1, H0,H1) \
        "s_waitcnt lgkmcnt(" CNT ")\n" \
        "v_pk_fma_f32 v[32:33], v[" A0 "], v[" H0 "], v[32:33]\n" \
        "v_pk_fma_f32 v[34:35], v[" B0 "], v[" H0 "], v[34:35]\n" \
        "v_pk_fma_f32 v[36:37], v[" C0 "], v[" H0 "], v[36:37]\n" \
        "v_pk_fma_f32 v[38:39], v[" D0 "], v[" H0 "], v[38:39]\n" \
        "v_pk_fma_f32 v[32:33], v[" A1 "], v[" H1 "], v[32:33]\n" \
        "v_pk_fma_f32 v[34:35], v[" B1 "], v[" H1 "], v[34:35]\n" \
        "v_pk_fma_f32 v[36:37], v[" C1 "], v[" H1 "], v[36:37]\n" \
        "v_pk_fma_f32 v[38:39], v[" D1 "], v[" H1 "], v[38:39]\n"

// One timestep. XNR = x set loaded this step (x_{t+2});
// XCR = x set loaded last step (x_{t+1}), written to LDS now; VC = vmcnt.
#define FBODY(XNR, XCR, VC) \
        /* x_{t+2} prefetch (32 masked lanes); clamp final plane */ \
        "s_and_saveexec_b64 s[86:87], %[mskx]\n" \
        "global_load_dwordx4 " XNR ", v18, %[xb]\n" \
        "s_mov_b64 exec, s[86:87]\n" \
        "v_add_u32 v18, 0x20000, v18\n" \
        "v_min_u32 v18, %[vxomax], v18\n" \
        /* issue 6 h quads */ \
        "ds_read_b128 v[40:43], v16\n" \
        "ds_read_b128 v[44:47], v16 offset:16\n" \
        "ds_read_b128 v[48:51], v16 offset:32\n" \
        "ds_read_b128 v[52:55], v16 offset:48\n" \
        "ds_read_b128 v[56:59], v16 offset:64\n" \
        "ds_read_b128 v[60:63], v16 offset:80\n" \
        /* Wh m=0: pk_mul init; reissue <- h quad6 */ \
        "s_waitcnt lgkmcnt(5)\n" \
        "v_pk_mul_f32 v[32:33], v[64:65],   v[40:41]\n" \
        "v_pk_mul_f32 v[34:35], v[96:97],   v[40:41]\n" \
        "v_pk_mul_f32 v[36:37], v[128:129], v[40:41]\n" \
        "v_pk_mul_f32 v[38:39], v[160:161], v[40:41]\n" \
        "v_pk_fma_f32 v[32:33], v[66:67],   v[42:43], v[32:33]\n" \
        "v_pk_fma_f32 v[34:35], v[98:99],   v[42:43], v[34:35]\n" \
        "v_pk_fma_f32 v[36:37], v[130:131], v[42:43], v[36:37]\n" \
        "v_pk_fma_f32 v[38:39], v[162:163], v[42:43], v[38:39]\n" \
        "ds_read_b128 v[40:43], v16 offset:96\n" \
        FCHUNK("5","68:69","70:71","100:101","102:103","132:133","134:135","164:165","166:167","44:45","46:47") \
        "ds_read_b128 v[44:47], v16 offset:112\n" \
        FCHUNK("5","72:73","74:75","104:105","106:107","136:137","138:139","168:169","170:171","48:49","50:51") \
        "ds_read_b128 v[48:51], v16 offset:128\n" \
        FCHUNK("5","76:77","78:79","108:109","110:111","140:141","142:143","172:173","174:175","52:53","54:55") \
        "ds_read_b128 v[52:55], v16 offset:144\n" \
        FCHUNK("5","80:81","82:83","112:113","114:115","144:145","146:147","176:177","178:179","56:57","58:59") \
        "ds_read_b128 v[56:59], v16 offset:160\n" \
        FCHUNK("5","84:85","86:87","116:117","118:119","148:149","150:151","180:181","182:183","60:61","62:63") \
        "ds_read_b128 v[60:63], v16 offset:176\n" \
        FCHUNK("5","88:89","90:91","120:121","122:123","152:153","154:155","184:185","186:187","40:41","42:43") \
        FCHUNK("4","92:93","94:95","124:125","126:127","156:157","158:159","188:189","190:191","44:45","46:47") \
        FCHUNK("3","192:193","194:195","208:209","210:211","224:225","226:227","240:241","242:243","48:49","50:51") \
        FCHUNK("2","196:197","198:199","212:213","214:215","228:229","230:231","244:245","246:247","52:53","54:55") \
        FCHUNK("1","200:201","202:203","216:217","218:219","232:233","234:235","248:249","250:251","56:57","58:59") \
        FCHUNK("0","204:205","206:207","220:221","222:223","236:237","238:239","252:253","254:255","60:61","62:63") \
        /* x stage write (x_{t+1}; loaded 2 bodies of latency ago) */ \
        "s_waitcnt vmcnt(" VC ")\n" \
        "s_and_saveexec_b64 s[86:87], %[mskx]\n" \
        "ds_write_b128 v24, " XCR "\n" \
        "s_mov_b64 exec, s[86:87]\n" \
        "v_xor_b32 v24, 0x800, v24\n" \
        /* merge pk pairs -> v32,v34,v36,v38 (acc regs dead; frees v26-29) */ \
        "v_add_f32 v32, v32, v33\n" \
        "v_add_f32 v34, v34, v35\n" \
        "v_add_f32 v36, v36, v37\n" \
        "v_add_f32 v38, v38, v39\n" \
        /* butterfly xor1/xor2/xor8 (all producer->DPP gaps = 3 >= 2) */ \
        "v_add_f32 v32, v32, v32 quad_perm:[1,0,3,2] row_mask:0xf bank_mask:0xf\n" \
        "v_add_f32 v34, v34, v34 quad_perm:[1,0,3,2] row_mask:0xf bank_mask:0xf\n" \
        "v_add_f32 v36, v36, v36 quad_perm:[1,0,3,2] row_mask:0xf bank_mask:0xf\n" \
        "v_add_f32 v38, v38, v38 quad_perm:[1,0,3,2] row_mask:0xf bank_mask:0xf\n" \
        "v_add_f32 v32, v32, v32 quad_perm:[2,3,0,1] row_mask:0xf bank_mask:0xf\n" \
        "v_add_f32 v34, v34, v34 quad_perm:[2,3,0,1] row_mask:0xf bank_mask:0xf\n" \
        "v_add_f32 v36, v36, v36 quad_perm:[2,3,0,1] row_mask:0xf bank_mask:0xf\n" \
        "v_add_f32 v38, v38, v38 quad_perm:[2,3,0,1] row_mask:0xf bank_mask:0xf\n" \
        "v_add_f32 v32, v32, v32 row_ror:8 row_mask:0xf bank_mask:0xf\n" \
        "v_add_f32 v34, v34, v34 row_ror:8 row_mask:0xf bank_mask:0xf\n" \
        "v_add_f32 v36, v36, v36 row_ror:8 row_mask:0xf bank_mask:0xf\n" \
        "v_add_f32 v38, v38, v38 row_ror:8 row_mask:0xf bank_mask:0xf\n" \
        /* select this lane's column (kg&3) */ \
        "v_cndmask_b32 v30, v32, v34, %[m0]\n" \
        "v_cndmask_b32 v31, v36, v38, %[m0]\n" \
        "v_cndmask_b32 v30, v30, v31, %[m1]\n" \
        /* + bh*S ; tanh = 1 - 2*rcp(exp2(arg)+1) */ \
        "v_add_f32 v30, v30, v19\n" \
        "v_exp_f32 v31, v30\n" \
        "s_nop 0\n" \
        "v_add_f32 v31, 1.0, v31\n" \
        "v_rcp_f32 v31, v31\n" \
        "s_nop 0\n" \
        "v_fma_f32 v30, -2.0, v31, 1.0\n" \
        /* masked h LDS write (kg<4) */ \
        "s_and_saveexec_b64 s[84:85], %[msk]\n" \
        "ds_write_b32 v17, v30\n" \
        "s_mov_b64 exec, s[84:85]\n" \
        "v_xor_b32 v17, 0x800, v17\n" \
        /* global h store (all lanes; dup addrs merge) */ \
        "global_store_dword v25, v30, %[iob]\n" \
        "v_add_u32 v25, 0x40000, v25\n" \
        "s_waitcnt lgkmcnt(0)\n" \
        "s_barrier\n" \
        "v_xor_b32 v16, 0x800, v16\n"

#define SCALE_PAIR(P) "v_pk_mul_f32 v[" P "], v[" P "], v[26:27]\n"

__global__ __launch_bounds__(512, 2) void rnn_fused_kernel(
    const float* __restrict__ x,  const float* __restrict__ h0,
    const float* __restrict__ Wi, const float* __restrict__ Wh,
    const float* __restrict__ bh, float* __restrict__ out)
{
    __shared__ float hbuf[928];  // buf0 [0,1664B) buf1 [0x800,+1664B)

    const int tid  = threadIdx.x;
    const int b    = blockIdx.x;
    const int lane = tid & 63;
    const int q    = tid >> 6;                       // wave id 0..7
    const int kg   = (lane & 3) | ((lane >> 1) & 4); // 0..7
    const int cg   = ((lane >> 2) & 1) | ((lane >> 3) & 6); // 0..7
    const int col0 = 32 * q + 4 * cg;
    const int col  = col0 + (kg & 3);                // finalize column

    const float* wp  = Wh + (size_t)col0 * HH + kg * 32;  // Wh frag base
    const float* wip = Wi + (size_t)col0 * II + kg * 16;  // Wi frag base
    const float* iob = out + (size_t)b * HH;              // h store base
    const float* xb  = x   + (size_t)b * II;              // x load base
    unsigned hbase = (unsigned)(size_t)&hbuf[0];
    unsigned hvr = hbase + kg * 208;                      // read base (buf0)
    unsigned hvw = hbase + 0x800 + q * 208 + (4 * cg + (kg & 3)) * 4;
    unsigned vxw = hbase + 0x800 + (tid >> 2) * 208 + 128 + 16 * (tid & 3);
    unsigned vxo = (unsigned)(16 * tid) + 0x20000u;       // x plane 1
    unsigned vxomax = (unsigned)(16 * tid) + 511u * 0x20000u;
    unsigned vho = (unsigned)(col * 4);                   // h store ofs
    float bhv = bh[col] * TANH_S;
    unsigned long long m0   = __ballot((lane & 1) != 0);
    unsigned long long m1   = __ballot((lane & 2) != 0);
    unsigned long long msk  = __ballot(kg < 4);           // h LDS writers
    unsigned long long mskx = __ballot(tid < 32);         // x stagers

    // stage h0 + x0 into buffer 0 (group-interleaved layout)
    if (tid < HH) hbuf[(tid >> 5) * 52 + (tid & 31)] = h0[(size_t)b * HH + tid];
    if (tid < II) hbuf[(tid >> 4) * 52 + 32 + (tid & 15)] = xb[tid];
    __syncthreads();

    asm volatile(
        // ---- Wh fragment: col j quad m -> v[64+32j+4m] ----
        "global_load_dwordx4 v[64:67],   %[wp], off\n"
        "global_load_dwordx4 v[68:71],   %[wp], off offset:16\n"
        "global_load_dwordx4 v[72:75],   %[wp], off offset:32\n"
        "global_load_dwordx4 v[76:79],   %[wp], off offset:48\n"
        "global_load_dwordx4 v[80:83],   %[wp], off offset:64\n"
        "global_load_dwordx4 v[84:87],   %[wp], off offset:80\n"
        "global_load_dwordx4 v[88:91],   %[wp], off offset:96\n"
        "global_load_dwordx4 v[92:95],   %[wp], off offset:112\n"
        "global_load_dwordx4 v[96:99],   %[wp], off offset:1024\n"
        "global_load_dwordx4 v[100:103], %[wp], off offset:1040\n"
        "global_load_dwordx4 v[104:107], %[wp], off offset:1056\n"
        "global_load_dwordx4 v[108:111], %[wp], off offset:1072\n"
        "global_load_dwordx4 v[112:115], %[wp], off offset:1088\n"
        "global_load_dwordx4 v[116:119], %[wp], off offset:1104\n"
        "global_load_dwordx4 v[120:123], %[wp], off offset:1120\n"
        "global_load_dwordx4 v[124:127], %[wp], off offset:1136\n"
        "global_load_dwordx4 v[128:131], %[wp], off offset:2048\n"
        "global_load_dwordx4 v[132:135], %[wp], off offset:2064\n"
        "global_load_dwordx4 v[136:139], %[wp], off offset:2080\n"
        "global_load_dwordx4 v[140:143], %[wp], off offset:2096\n"
        "global_load_dwordx4 v[144:147], %[wp], off offset:2112\n"
        "global_load_dwordx4 v[148:151], %[wp], off offset:2128\n"
        "global_load_dwordx4 v[152:155], %[wp], off offset:2144\n"
        "global_load_dwordx4 v[156:159], %[wp], off offset:2160\n"
        "global_load_dwordx4 v[160:163], %[wp], off offset:3072\n"
        "global_load_dwordx4 v[164:167], %[wp], off offset:3088\n"
        "global_load_dwordx4 v[168:171], %[wp], off offset:3104\n"
        "global_load_dwordx4 v[172:175], %[wp], off offset:3120\n"
        "global_load_dwordx4 v[176:179], %[wp], off offset:3136\n"
        "global_load_dwordx4 v[180:183], %[wp], off offset:3152\n"
        "global_load_dwordx4 v[184:187], %[wp], off offset:3168\n"
        "global_load_dwordx4 v[188:191], %[wp], off offset:3184\n"
        // ---- Wi fragment: col j quad n -> v[192+16j+4n] ----
        "global_load_dwordx4 v[192:195], %[wip], off\n"
        "global_load_dwordx4 v[196:199], %[wip], off offset:16\n"
        "global_load_dwordx4 v[200:203], %[wip], off offset:32\n"
        "global_load_dwordx4 v[204:207], %[wip], off offset:48\n"
        "global_load_dwordx4 v[208:211], %[wip], off offset:512\n"
        "global_load_dwordx4 v[212:215], %[wip], off offset:528\n"
        "global_load_dwordx4 v[216:219], %[wip], off offset:544\n"
        "global_load_dwordx4 v[220:223], %[wip], off offset:560\n"
        "global_load_dwordx4 v[224:227], %[wip], off offset:1024\n"
        "global_load_dwordx4 v[228:231], %[wip], off offset:1040\n"
        "global_load_dwordx4 v[232:235], %[wip], off offset:1056\n"
        "global_load_dwordx4 v[236:239], %[wip], off offset:1072\n"
        "global_load_dwordx4 v[240:243], %[wip], off offset:1536\n"
        "global_load_dwordx4 v[244:247], %[wip], off offset:1552\n"
        "global_load_dwordx4 v[248:251], %[wip], off offset:1568\n"
        "global_load_dwordx4 v[252:255], %[wip], off offset:1584\n"
        // ---- init ----
        "v_mov_b32 v16, %[hvr]\n"
        "v_mov_b32 v17, %[hvw]\n"
        "v_mov_b32 v18, %[vxo]\n"
        "v_mov_b32 v19, %[bhv]\n"
        "v_mov_b32 v24, %[vxw]\n"
        "v_mov_b32 v25, %[vho]\n"
        "s_waitcnt vmcnt(0)\n"
        // ---- one-time pre-scale of Wh+Wi fragments by 2*log2(e) ----
        "v_mov_b32 v26, 0x4038aa3b\n"
        "v_mov_b32 v27, 0x4038aa3b\n"
        SCALE_PAIR("64:65")   SCALE_PAIR("66:67")   SCALE_PAIR("68:69")   SCALE_PAIR("70:71")
        SCALE_PAIR("72:73")   SCALE_PAIR("74:75")   SCALE_PAIR("76:77")   SCALE_PAIR("78:79")
        SCALE_PAIR("80:81")   SCALE_PAIR("82:83")   SCALE_PAIR("84:85")   SCALE_PAIR("86:87")
        SCALE_PAIR("88:89")   SCALE_PAIR("90:91")   SCALE_PAIR("92:93")   SCALE_PAIR("94:95")
        SCALE_PAIR("96:97")   SCALE_PAIR("98:99")   SCALE_PAIR("100:101") SCALE_PAIR("102:103")
        SCALE_PAIR("104:105") SCALE_PAIR("106:107") SCALE_PAIR("108:109") SCALE_PAIR("110:111")
        SCALE_PAIR("112:113") SCALE_PAIR("114:115") SCALE_PAIR("116:117") SCALE_PAIR("118:119")
        SCALE_PAIR("120:121") SCALE_PAIR("122:123") SCALE_PAIR("124:125") SCALE_PAIR("126:127")
        SCALE_PAIR("128:129") SCALE_PAIR("130:131") SCALE_PAIR("132:133") SCALE_PAIR("134:135")
        SCALE_PAIR("136:137") SCALE_PAIR("138:139") SCALE_PAIR("140:141") SCALE_PAIR("142:143")
        SCALE_PAIR("144:145") SCALE_PAIR("146:147") SCALE_PAIR("148:149") SCALE_PAIR("150:151")
        SCALE_PAIR("152:153") SCALE_PAIR("154:155") SCALE_PAIR("156:157") SCALE_PAIR("158:159")
        SCALE_PAIR("160:161") SCALE_PAIR("162:163") SCALE_PAIR("164:165") SCALE_PAIR("166:167")
        SCALE_PAIR("168:169") SCALE_PAIR("170:171") SCALE_PAIR("172:173") SCALE_PAIR("174:175")
        SCALE_PAIR("176:177") SCALE_PAIR("178:179") SCALE_PAIR("180:181") SCALE_PAIR("182:183")
        SCALE_PAIR("184:185") SCALE_PAIR("186:187") SCALE_PAIR("188:189") SCALE_PAIR("190:191")
        SCALE_PAIR("192:193") SCALE_PAIR("194:195") SCALE_PAIR("196:197") SCALE_PAIR("198:199")
        SCALE_PAIR("200:201") SCALE_PAIR("202:203") SCALE_PAIR("204:205") SCALE_PAIR("206:207")
        SCALE_PAIR("208:209") SCALE_PAIR("210:211") SCALE_PAIR("212:213") SCALE_PAIR("214:215")
        SCALE_PAIR("216:217") SCALE_PAIR("218:219") SCALE_PAIR("220:221") SCALE_PAIR("222:223")
        SCALE_PAIR("224:225") SCALE_PAIR("226:227") SCALE_PAIR("228:229") SCALE_PAIR("230:231")
        SCALE_PAIR("232:233") SCALE_PAIR("234:235") SCALE_PAIR("236:237") SCALE_PAIR("238:239")
        SCALE_PAIR("240:241") SCALE_PAIR("242:243") SCALE_PAIR("244:245") SCALE_PAIR("246:247")
        SCALE_PAIR("248:249") SCALE_PAIR("250:251") SCALE_PAIR("252:253") SCALE_PAIR("254:255")
        // ---- prologue: x_1 -> XB (v26-29); advance to plane 2 ----
        "s_and_saveexec_b64 s[86:87], %[mskx]\n"
        "global_load_dwordx4 v[26:29], v18, %[xb]\n"
        "s_mov_b64 exec, s[86:87]\n"
        "v_add_u32 v18, 0x20000, v18\n"
        "s_movk_i32 s82, 0xFF\n"
        // ---- peeled step 0 (vmcnt(0): XB not yet countable as "+2") ----
        FBODY("v[20:23]", "v[26:29]", "0")
        // ---- peeled step 1 (steady-state count from here) ----
        FBODY("v[26:29]", "v[20:23]", "2")
        "LTOP_%=:\n"
        FBODY("v[20:23]", "v[26:29]", "2")
        FBODY("v[26:29]", "v[20:23]", "2")
        "s_sub_u32 s82, s82, 1\n"
        "s_cmp_lg_u32 s82, 0\n"
        "s_cbranch_scc1 LTOP_%=\n"
        :
        : [wp] "v"(wp), [wip] "v"(wip), [iob] "s"(iob), [xb] "s"(xb),
          [hvr] "v"(hvr), [hvw] "v"(hvw), [vxo] "v"(vxo),
          [vxomax] "v"(vxomax), [vxw] "v"(vxw), [vho] "v"(vho),
          [bhv] "v"(bhv),
          [m0] "s"(m0), [m1] "s"(m1), [msk] "s"(msk), [mskx] "s"(mskx)
        : "memory", "scc", "s82", "s84", "s85", "s86", "s87",
          "v16","v17","v18","v19","v20","v21","v22","v23",
          "v24","v25","v26","v27","v28","v29","v30","v31",
          "v32","v33","v34","v35","v36","v37","v38","v39",
          "v40","v41","v42","v43","v44","v45","v46","v47",
          "v48","v49","v50","v51","v52","v53","v54","v55",
          "v56","v57","v58","v59","v60","v61","v62","v63",
          "v64","v65","v66","v67","v68","v69","v70","v71",
          "v72","v73","v74","v75","v76","v77","v78","v79",
          "v80","v81","v82","v83","v84","v85","v86","v87",
          "v88","v89","v90","v91","v92","v93","v94","v95",
          "v96","v97","v98","v99","v100","v101","v102","v103",
          "v104","v105","v106","v107","v108","v109","v110","v111",
          "v112","v113","v114","v115","v116","v117","v118","v119",
          "v120","v121","v122","v123","v124","v125","v126","v127",
          "v128","v129","v130","v131","v132","v133","v134","v135",
          "v136","v137","v138","v139","v140","v141","v142","v143",
          "v144","v145","v146","v147","v148","v149","v150","v151",
          "v152","v153","v154","v155","v156","v157","v158","v159",
          "v160","v161","v162","v163","v164","v165","v166","v167",
          "v168","v169","v170","v171","v172","v173","v174","v175",
          "v176","v177","v178","v179","v180","v181","v182","v183",
          "v184","v185","v186","v187","v188","v189","v190","v191",
          "v192","v193","v194","v195","v196","v197","v198","v199",
          "v200","v201","v202","v203","v204","v205","v206","v207",
          "v208","v209","v210","v211","v212","v213","v214","v215",
          "v216","v217","v218","v219","v220","v221","v222","v223",
          "v224","v225","v226","v227","v228","v229","v230","v231",
          "v232","v233","v234","v235","v236","v237","v238","v239",
          "v240","v241","v242","v243","v244","v245","v246","v247",
          "v248","v249","v250","v251","v252","v253","v254","v255");
}

extern "C" void kernel_launch(void* const* d_in, const int* in_sizes, int n_in,
                              void* d_out, int out_size, void* d_ws, size_t ws_size,
                              hipStream_t stream) {
    const float* x  = (const float*)d_in[0];  // [T,B,I]
    const float* h0 = (const float*)d_in[1];  // [B,H]
    const float* Wi = (const float*)d_in[2];  // [H,I]
    const float* Wh = (const float*)d_in[3];  // [H,H]
    const float* bh = (const float*)d_in[4];  // [H]
    float* out = (float*)d_out;               // [T,B,H]

    rnn_fused_kernel<<<BB, 512, 0, stream>>>(x, h0, Wi, Wh, bh, out);
}

// Round 17
// 326.075 us; speedup vs baseline: 1.3338x; 1.0348x over previous
//
#include <hip/hip_runtime.h>
#include <hip/hip_bf16.h>
#include <math.h>

// Problem dims (fixed): T=512, B=256, I=128, H=256
#define TT 512
#define BB 256
#define II 128
#define HH 256

// 2*log2(e): Wh, Wi, bh pre-scaled so tanh is exp2-direct.
#define TANH_S 2.885390043258667f

// ---------------------------------------------------------------------------
// Single fused kernel: h_t = tanh(Wh·h_{t-1} + Wi·x_t + bh), out[t] = h_t.
// r16 structure (fused augmented-K dot, 512 thr = 8 waves, 1 block/row,
// one barrier/step, 2-step-ahead x prefetch) + three scheduling cuts:
//   1. global h-store moved to the TOP of the next step (post-barrier):
//      fills part of the ~120cyc post-barrier ds_read latency hole and
//      shortens the pre-barrier tail. vmcnt: body0 (no store) = 1,
//      later bodies = 2 (store+x-load newer than consumed x-load).
//      Final h stored in an epilogue after the loop.
//   2. select-early butterfly (r13-proven): xor1+xor2 (8 DPP) -> 3 cndmask
//      -> s_nop 1 (DPP crossbar hazard fence) -> single row_ror:8.
//      3 fewer DPP ops, identical math.
//   3. s_setprio 1 around the FMA phase (T5).
// ---------------------------------------------------------------------------

#define FCHUNK(CNT, A0,A1,B0,B1,C0,C1,D0,D1, H0,H1) \
        "s_waitcnt lgkmcnt(" CNT ")\n" \
        "v_pk_fma_f32 v[32:33], v[" A0 "], v[" H0 "], v[32:33]\n" \
        "v_pk_fma_f32 v[34:35], v[" B0 "], v[" H0 "], v[34:35]\n" \
        "v_pk_fma_f32 v[36:37], v[" C0 "], v[" H0 "], v[36:37]\n" \
        "v_pk_fma_f32 v[38:39], v[" D0 "], v[" H0 "], v[38:39]\n" \
        "v_pk_fma_f32 v[32:33], v[" A1 "], v[" H1 "], v[32:33]\n" \
        "v_pk_fma_f32 v[34:35], v[" B1 "], v[" H1 "], v[34:35]\n" \
        "v_pk_fma_f32 v[36:37], v[" C1 "], v[" H1 "], v[36:37]\n" \
        "v_pk_fma_f32 v[38:39], v[" D1 "], v[" H1 "], v[38:39]\n"

// h_{t-1} global store, issued post-barrier at step-t top (fills the
// ds_read latency hole).  Omitted in the first peeled body.
#define HSTORE \
        "global_store_dword v25, v30, %[iob]\n" \
        "v_add_u32 v25, 0x40000, v25\n"

// One timestep. XNR = x set loaded this step (x_{t+2});
// XCR = x set loaded last step (x_{t+1}), written to LDS now;
// VC = vmcnt for the x LDS-write; ST = HSTORE or "".
#define FBODY(XNR, XCR, VC, ST) \
        ST \
        /* x_{t+2} prefetch (32 masked lanes); clamp final plane */ \
        "s_and_saveexec_b64 s[86:87], %[mskx]\n" \
        "global_load_dwordx4 " XNR ", v18, %[xb]\n" \
        "s_mov_b64 exec, s[86:87]\n" \
        "v_add_u32 v18, 0x20000, v18\n" \
        "v_min_u32 v18, %[vxomax], v18\n" \
        /* issue 6 h quads */ \
        "ds_read_b128 v[40:43], v16\n" \
        "ds_read_b128 v[44:47], v16 offset:16\n" \
        "ds_read_b128 v[48:51], v16 offset:32\n" \
        "ds_read_b128 v[52:55], v16 offset:48\n" \
        "ds_read_b128 v[56:59], v16 offset:64\n" \
        "ds_read_b128 v[60:63], v16 offset:80\n" \
        "s_setprio 1\n" \
        /* Wh m=0: pk_mul init; reissue <- h quad6 */ \
        "s_waitcnt lgkmcnt(5)\n" \
        "v_pk_mul_f32 v[32:33], v[64:65],   v[40:41]\n" \
        "v_pk_mul_f32 v[34:35], v[96:97],   v[40:41]\n" \
        "v_pk_mul_f32 v[36:37], v[128:129], v[40:41]\n" \
        "v_pk_mul_f32 v[38:39], v[160:161], v[40:41]\n" \
        "v_pk_fma_f32 v[32:33], v[66:67],   v[42:43], v[32:33]\n" \
        "v_pk_fma_f32 v[34:35], v[98:99],   v[42:43], v[34:35]\n" \
        "v_pk_fma_f32 v[36:37], v[130:131], v[42:43], v[36:37]\n" \
        "v_pk_fma_f32 v[38:39], v[162:163], v[42:43], v[38:39]\n" \
        "ds_read_b128 v[40:43], v16 offset:96\n" \
        FCHUNK("5","68:69","70:71","100:101","102:103","132:133","134:135","164:165","166:167","44:45","46:47") \
        "ds_read_b128 v[44:47], v16 offset:112\n" \
        FCHUNK("5","72:73","74:75","104:105","106:107","136:137","138:139","168:169","170:171","48:49","50:51") \
        "ds_read_b128 v[48:51], v16 offset:128\n" \
        FCHUNK("5","76:77","78:79","108:109","110:111","140:141","142:143","172:173","174:175","52:53","54:55") \
        "ds_read_b128 v[52:55], v16 offset:144\n" \
        FCHUNK("5","80:81","82:83","112:113","114:115","144:145","146:147","176:177","178:179","56:57","58:59") \
        "ds_read_b128 v[56:59], v16 offset:160\n" \
        FCHUNK("5","84:85","86:87","116:117","118:119","148:149","150:151","180:181","182:183","60:61","62:63") \
        "ds_read_b128 v[60:63], v16 offset:176\n" \
        FCHUNK("5","88:89","90:91","120:121","122:123","152:153","154:155","184:185","186:187","40:41","42:43") \
        FCHUNK("4","92:93","94:95","124:125","126:127","156:157","158:159","188:189","190:191","44:45","46:47") \
        FCHUNK("3","192:193","194:195","208:209","210:211","224:225","226:227","240:241","242:243","48:49","50:51") \
        FCHUNK("2","196:197","198:199","212:213","214:215","228:229","230:231","244:245","246:247","52:53","54:55") \
        FCHUNK("1","200:201","202:203","216:217","218:219","232:233","234:235","248:249","250:251","56:57","58:59") \
        FCHUNK("0","204:205","206:207","220:221","222:223","236:237","238:239","252:253","254:255","60:61","62:63") \
        "s_setprio 0\n" \
        /* x stage write (x_{t+1}; loaded one body ago) */ \
        "s_waitcnt vmcnt(" VC ")\n" \
        "s_and_saveexec_b64 s[86:87], %[mskx]\n" \
        "ds_write_b128 v24, " XCR "\n" \
        "s_mov_b64 exec, s[86:87]\n" \
        "v_xor_b32 v24, 0x800, v24\n" \
        /* merge pk pairs -> v32,v34,v36,v38 */ \
        "v_add_f32 v32, v32, v33\n" \
        "v_add_f32 v34, v34, v35\n" \
        "v_add_f32 v36, v36, v37\n" \
        "v_add_f32 v38, v38, v39\n" \
        /* xor1, xor2 (producer->DPP gaps = 3 >= 2) */ \
        "v_add_f32 v32, v32, v32 quad_perm:[1,0,3,2] row_mask:0xf bank_mask:0xf\n" \
        "v_add_f32 v34, v34, v34 quad_perm:[1,0,3,2] row_mask:0xf bank_mask:0xf\n" \
        "v_add_f32 v36, v36, v36 quad_perm:[1,0,3,2] row_mask:0xf bank_mask:0xf\n" \
        "v_add_f32 v38, v38, v38 quad_perm:[1,0,3,2] row_mask:0xf bank_mask:0xf\n" \
        "v_add_f32 v32, v32, v32 quad_perm:[2,3,0,1] row_mask:0xf bank_mask:0xf\n" \
        "v_add_f32 v34, v34, v34 quad_perm:[2,3,0,1] row_mask:0xf bank_mask:0xf\n" \
        "v_add_f32 v36, v36, v36 quad_perm:[2,3,0,1] row_mask:0xf bank_mask:0xf\n" \
        "v_add_f32 v38, v38, v38 quad_perm:[2,3,0,1] row_mask:0xf bank_mask:0xf\n" \
        /* select-early: this lane's column (kg&3) */ \
        "v_cndmask_b32 v30, v32, v34, %[m0]\n" \
        "v_cndmask_b32 v31, v36, v38, %[m0]\n" \
        "v_cndmask_b32 v30, v30, v31, %[m1]\n" \
        /* DPP crossbar hazard fence (r13-proven), then xor8 */ \
        "s_nop 1\n" \
        "v_add_f32 v30, v30, v30 row_ror:8 row_mask:0xf bank_mask:0xf\n" \
        /* + bh*S ; tanh = 1 - 2*rcp(exp2(arg)+1) */ \
        "v_add_f32 v30, v30, v19\n" \
        "v_exp_f32 v31, v30\n" \
        "s_nop 0\n" \
        "v_add_f32 v31, 1.0, v31\n" \
        "v_rcp_f32 v31, v31\n" \
        "s_nop 0\n" \
        "v_fma_f32 v30, -2.0, v31, 1.0\n" \
        /* masked h LDS write (kg<4) */ \
        "s_and_saveexec_b64 s[84:85], %[msk]\n" \
        "ds_write_b32 v17, v30\n" \
        "s_mov_b64 exec, s[84:85]\n" \
        "v_xor_b32 v17, 0x800, v17\n" \
        "s_waitcnt lgkmcnt(0)\n" \
        "s_barrier\n" \
        "v_xor_b32 v16, 0x800, v16\n"

#define SCALE_PAIR(P) "v_pk_mul_f32 v[" P "], v[" P "], v[26:27]\n"

__global__ __launch_bounds__(512, 2) void rnn_fused_kernel(
    const float* __restrict__ x,  const float* __restrict__ h0,
    const float* __restrict__ Wi, const float* __restrict__ Wh,
    const float* __restrict__ bh, float* __restrict__ out)
{
    __shared__ float hbuf[928];  // buf0 [0,1664B) buf1 [0x800,+1664B)

    const int tid  = threadIdx.x;
    const int b    = blockIdx.x;
    const int lane = tid & 63;
    const int q    = tid >> 6;                       // wave id 0..7
    const int kg   = (lane & 3) | ((lane >> 1) & 4); // 0..7
    const int cg   = ((lane >> 2) & 1) | ((lane >> 3) & 6); // 0..7
    const int col0 = 32 * q + 4 * cg;
    const int col  = col0 + (kg & 3);                // finalize column

    const float* wp  = Wh + (size_t)col0 * HH + kg * 32;  // Wh frag base
    const float* wip = Wi + (size_t)col0 * II + kg * 16;  // Wi frag base
    const float* iob = out + (size_t)b * HH;              // h store base
    const float* xb  = x   + (size_t)b * II;              // x load base
    unsigned hbase = (unsigned)(size_t)&hbuf[0];
    unsigned hvr = hbase + kg * 208;                      // read base (buf0)
    unsigned hvw = hbase + 0x800 + q * 208 + (4 * cg + (kg & 3)) * 4;
    unsigned vxw = hbase + 0x800 + (tid >> 2) * 208 + 128 + 16 * (tid & 3);
    unsigned vxo = (unsigned)(16 * tid) + 0x20000u;       // x plane 1
    unsigned vxomax = (unsigned)(16 * tid) + 511u * 0x20000u;
    unsigned vho = (unsigned)(col * 4);                   // h store ofs
    float bhv = bh[col] * TANH_S;
    unsigned long long m0   = __ballot((lane & 1) != 0);
    unsigned long long m1   = __ballot((lane & 2) != 0);
    unsigned long long msk  = __ballot(kg < 4);           // h LDS writers
    unsigned long long mskx = __ballot(tid < 32);         // x stagers

    // stage h0 + x0 into buffer 0 (group-interleaved layout)
    if (tid < HH) hbuf[(tid >> 5) * 52 + (tid & 31)] = h0[(size_t)b * HH + tid];
    if (tid < II) hbuf[(tid >> 4) * 52 + 32 + (tid & 15)] = xb[tid];
    __syncthreads();

    asm volatile(
        // ---- Wh fragment: col j quad m -> v[64+32j+4m] ----
        "global_load_dwordx4 v[64:67],   %[wp], off\n"
        "global_load_dwordx4 v[68:71],   %[wp], off offset:16\n"
        "global_load_dwordx4 v[72:75],   %[wp], off offset:32\n"
        "global_load_dwordx4 v[76:79],   %[wp], off offset:48\n"
        "global_load_dwordx4 v[80:83],   %[wp], off offset:64\n"
        "global_load_dwordx4 v[84:87],   %[wp], off offset:80\n"
        "global_load_dwordx4 v[88:91],   %[wp], off offset:96\n"
        "global_load_dwordx4 v[92:95],   %[wp], off offset:112\n"
        "global_load_dwordx4 v[96:99],   %[wp], off offset:1024\n"
        "global_load_dwordx4 v[100:103], %[wp], off offset:1040\n"
        "global_load_dwordx4 v[104:107], %[wp], off offset:1056\n"
        "global_load_dwordx4 v[108:111], %[wp], off offset:1072\n"
        "global_load_dwordx4 v[112:115], %[wp], off offset:1088\n"
        "global_load_dwordx4 v[116:119], %[wp], off offset:1104\n"
        "global_load_dwordx4 v[120:123], %[wp], off offset:1120\n"
        "global_load_dwordx4 v[124:127], %[wp], off offset:1136\n"
        "global_load_dwordx4 v[128:131], %[wp], off offset:2048\n"
        "global_load_dwordx4 v[132:135], %[wp], off offset:2064\n"
        "global_load_dwordx4 v[136:139], %[wp], off offset:2080\n"
        "global_load_dwordx4 v[140:143], %[wp], off offset:2096\n"
        "global_load_dwordx4 v[144:147], %[wp], off offset:2112\n"
        "global_load_dwordx4 v[148:151], %[wp], off offset:2128\n"
        "global_load_dwordx4 v[152:155], %[wp], off offset:2144\n"
        "global_load_dwordx4 v[156:159], %[wp], off offset:2160\n"
        "global_load_dwordx4 v[160:163], %[wp], off offset:3072\n"
        "global_load_dwordx4 v[164:167], %[wp], off offset:3088\n"
        "global_load_dwordx4 v[168:171], %[wp], off offset:3104\n"
        "global_load_dwordx4 v[172:175], %[wp], off offset:3120\n"
        "global_load_dwordx4 v[176:179], %[wp], off offset:3136\n"
        "global_load_dwordx4 v[180:183], %[wp], off offset:3152\n"
        "global_load_dwordx4 v[184:187], %[wp], off offset:3168\n"
        "global_load_dwordx4 v[188:191], %[wp], off offset:3184\n"
        // ---- Wi fragment: col j quad n -> v[192+16j+4n] ----
        "global_load_dwordx4 v[192:195], %[wip], off\n"
        "global_load_dwordx4 v[196:199], %[wip], off offset:16\n"
        "global_load_dwordx4 v[200:203], %[wip], off offset:32\n"
        "global_load_dwordx4 v[204:207], %[wip], off offset:48\n"
        "global_load_dwordx4 v[208:211], %[wip], off offset:512\n"
        "global_load_dwordx4 v[212:215], %[wip], off offset:528\n"
        "global_load_dwordx4 v[216:219], %[wip], off offset:544\n"
        "global_load_dwordx4 v[220:223], %[wip], off offset:560\n"
        "global_load_dwordx4 v[224:227], %[wip], off offset:1024\n"
        "global_load_dwordx4 v[228:231], %[wip], off offset:1040\n"
        "global_load_dwordx4 v[232:235], %[wip], off offset:1056\n"
        "global_load_dwordx4 v[236:239], %[wip], off offset:1072\n"
        "global_load_dwordx4 v[240:243], %[wip], off offset:1536\n"
        "global_load_dwordx4 v[244:247], %[wip], off offset:1552\n"
        "global_load_dwordx4 v[248:251], %[wip], off offset:1568\n"
        "global_load_dwordx4 v[252:255], %[wip], off offset:1584\n"
        // ---- init ----
        "v_mov_b32 v16, %[hvr]\n"
        "v_mov_b32 v17, %[hvw]\n"
        "v_mov_b32 v18, %[vxo]\n"
        "v_mov_b32 v19, %[bhv]\n"
        "v_mov_b32 v24, %[vxw]\n"
        "v_mov_b32 v25, %[vho]\n"
        "s_waitcnt vmcnt(0)\n"
        // ---- one-time pre-scale of Wh+Wi fragments by 2*log2(e) ----
        "v_mov_b32 v26, 0x4038aa3b\n"
        "v_mov_b32 v27, 0x4038aa3b\n"
        SCALE_PAIR("64:65")   SCALE_PAIR("66:67")   SCALE_PAIR("68:69")   SCALE_PAIR("70:71")
        SCALE_PAIR("72:73")   SCALE_PAIR("74:75")   SCALE_PAIR("76:77")   SCALE_PAIR("78:79")
        SCALE_PAIR("80:81")   SCALE_PAIR("82:83")   SCALE_PAIR("84:85")   SCALE_PAIR("86:87")
        SCALE_PAIR("88:89")   SCALE_PAIR("90:91")   SCALE_PAIR("92:93")   SCALE_PAIR("94:95")
        SCALE_PAIR("96:97")   SCALE_PAIR("98:99")   SCALE_PAIR("100:101") SCALE_PAIR("102:103")
        SCALE_PAIR("104:105") SCALE_PAIR("106:107") SCALE_PAIR("108:109") SCALE_PAIR("110:111")
        SCALE_PAIR("112:113") SCALE_PAIR("114:115") SCALE_PAIR("116:117") SCALE_PAIR("118:119")
        SCALE_PAIR("120:121") SCALE_PAIR("122:123") SCALE_PAIR("124:125") SCALE_PAIR("126:127")
        SCALE_PAIR("128:129") SCALE_PAIR("130:131") SCALE_PAIR("132:133") SCALE_PAIR("134:135")
        SCALE_PAIR("136:137") SCALE_PAIR("138:139") SCALE_PAIR("140:141") SCALE_PAIR("142:143")
        SCALE_PAIR("144:145") SCALE_PAIR("146:147") SCALE_PAIR("148:149") SCALE_PAIR("150:151")
        SCALE_PAIR("152:153") SCALE_PAIR("154:155") SCALE_PAIR("156:157") SCALE_PAIR("158:159")
        SCALE_PAIR("160:161") SCALE_PAIR("162:163") SCALE_PAIR("164:165") SCALE_PAIR("166:167")
        SCALE_PAIR("168:169") SCALE_PAIR("170:171") SCALE_PAIR("172:173") SCALE_PAIR("174:175")
        SCALE_PAIR("176:177") SCALE_PAIR("178:179") SCALE_PAIR("180:181") SCALE_PAIR("182:183")
        SCALE_PAIR("184:185") SCALE_PAIR("186:187") SCALE_PAIR("188:189") SCALE_PAIR("190:191")
        SCALE_PAIR("192:193") SCALE_PAIR("194:195") SCALE_PAIR("196:197") SCALE_PAIR("198:199")
        SCALE_PAIR("200:201") SCALE_PAIR("202:203") SCALE_PAIR("204:205") SCALE_PAIR("206:207")
        SCALE_PAIR("208:209") SCALE_PAIR("210:211") SCALE_PAIR("212:213") SCALE_PAIR("214:215")
        SCALE_PAIR("216:217") SCALE_PAIR("218:219") SCALE_PAIR("220:221") SCALE_PAIR("222:223")
        SCALE_PAIR("224:225") SCALE_PAIR("226:227") SCALE_PAIR("228:229") SCALE_PAIR("230:231")
        SCALE_PAIR("232:233") SCALE_PAIR("234:235") SCALE_PAIR("236:237") SCALE_PAIR("238:239")
        SCALE_PAIR("240:241") SCALE_PAIR("242:243") SCALE_PAIR("244:245") SCALE_PAIR("246:247")
        SCALE_PAIR("248:249") SCALE_PAIR("250:251") SCALE_PAIR("252:253") SCALE_PAIR("254:255")
        // ---- prologue: x_1 -> XB (v26-29); advance to plane 2 ----
        "s_and_saveexec_b64 s[86:87], %[mskx]\n"
        "global_load_dwordx4 v[26:29], v18, %[xb]\n"
        "s_mov_b64 exec, s[86:87]\n"
        "v_add_u32 v18, 0x20000, v18\n"
        "s_movk_i32 s82, 0xFF\n"
        // ---- peeled step 0 (no h store yet; vmcnt(1) = only body0's
        //      x-load newer than prologue's x_1 load) ----
        FBODY("v[20:23]", "v[26:29]", "1", "")
        // ---- peeled step 1 (steady-state: store + vmcnt(2)) ----
        FBODY("v[26:29]", "v[20:23]", "2", HSTORE)
        "LTOP_%=:\n"
        FBODY("v[20:23]", "v[26:29]", "2", HSTORE)
        FBODY("v[26:29]", "v[20:23]", "2", HSTORE)
        "s_sub_u32 s82, s82, 1\n"
        "s_cmp_lg_u32 s82, 0\n"
        "s_cbranch_scc1 LTOP_%=\n"
        // ---- epilogue: store h_T (deferred from the last body) ----
        "global_store_dword v25, v30, %[iob]\n"
        :
        : [wp] "v"(wp), [wip] "v"(wip), [iob] "s"(iob), [xb] "s"(xb),
          [hvr] "v"(hvr), [hvw] "v"(hvw), [vxo] "v"(vxo),
          [vxomax] "v"(vxomax), [vxw] "v"(vxw), [vho] "v"(vho),
          [bhv] "v"(bhv),
          [m0] "s"(m0), [m1] "s"(m1), [msk] "s"(msk), [mskx] "s"(mskx)
        : "memory", "scc", "s82", "s84", "s85", "s86", "s87",
          "v16","v17","v18","v19","v20","v21","v22","v23",
          "v24","v25","v26","v27","v28","v29","v30","v31",
          "v32","v33","v34","v35","v36","v37","v38","v39",
          "v40","v41","v42","v43","v44","v45","v46","v47",
          "v48","v49","v50","v51","v52","v53","v54","v55",
          "v56","v57","v58","v59","v60","v61","v62","v63",
          "v64","v65","v66","v67","v68","v69","v70","v71",
          "v72","v73","v74","v75","v76","v77","v78","v79",
          "v80","v81","v82","v83","v84","v85","v86","v87",
          "v88","v89","v90","v91","v92","v93","v94","v95",
          "v96","v97","v98","v99","v100","v101","v102","v103",
          "v104","v105","v106","v107","v108","v109","v110","v111",
          "v112","v113","v114","v115","v116","v117","v118","v119",
          "v120","v121","v122","v123","v124","v125","v126","v127",
          "v128","v129","v130","v131","v132","v133","v134","v135",
          "v136","v137","v138","v139","v140","v141","v142","v143",
          "v144","v145","v146","v147","v148","v149","v150","v151",
          "v152","v153","v154","v155","v156","v157","v158","v159",
          "v160","v161","v162","v163","v164","v165","v166","v167",
          "v168","v169","v170","v171","v172","v173","v174","v175",
          "v176","v177","v178","v179","v180","v181","v182","v183",
          "v184","v185","v186","v187","v188","v189","v190","v191",
          "v192","v193","v194","v195","v196","v197","v198","v199",
          "v200","v201","v202","v203","v204","v205","v206","v207",
          "v208","v209","v210","v211","v212","v213","v214","v215",
          "v216","v217","v218","v219","v220","v221","v222","v223",
          "v224","v225","v226","v227","v228","v229","v230","v231",
          "v232","v233","v234","v235","v236","v237","v238","v239",
          "v240","v241","v242","v243","v244","v245","v246","v247",
          "v248","v249","v250","v251","v252","v253","v254","v255");
}

extern "C" void kernel_launch(void* const* d_in, const int* in_sizes, int n_in,
                              void* d_out, int out_size, void* d_ws, size_t ws_size,
                              hipStream_t stream) {
    const float* x  = (const float*)d_in[0];  // [T,B,I]
    const float* h0 = (const float*)d_in[1];  // [B,H]
    const float* Wi = (const float*)d_in[2];  // [H,I]
    const float* Wh = (const float*)d_in[3];  // [H,H]
    const float* bh = (const float*)d_in[4];  // [H]
    float* out = (float*)d_out;               // [T,B,H]

    rnn_fused_kernel<<<BB, 512, 0, stream>>>(x, h0, Wi, Wh, bh, out);
}

// Round 20
// 325.912 us; speedup vs baseline: 1.3345x; 1.0005x over previous
//
#include <hip/hip_runtime.h>
#include <hip/hip_bf16.h>
#include <math.h>

// Problem dims (fixed): T=512, B=256, I=128, H=256
#define TT 512
#define BB 256
#define II 128
#define HH 256

// 2*log2(e): Wh, Wi, bh pre-scaled so tanh is exp2-direct.
#define TANH_S 2.885390043258667f

// ---------------------------------------------------------------------------
// Single fused kernel: h_t = tanh(Wh·h_{t-1} + Wi·x_t + bh), out[t] = h_t.
// r18 structure (per-wave private x staging, PRE-BARRIER x reads, maskless
// x path) with BOTH bugs fixed:
//   r18 bug: x double-buffer XOR 0x2000 crossed its own bit boundary
//     (x region 0x1000-0x23FF) -> waves 6-7 wrapped into the h region.
//     Fixed: buf1 at +0x4000 (bit 14 constant over each buffer).
//   r19 bug: a stray identity-DPP line in the merge ("v38 = 2*v38") made
//     every (kg&3)==3 column wrong. Fixed: clean 4-add merge (r18 form).
// LDS: h 2x(8 groups x 144B) at 0/0x800; x buf0 at 0x1000 (8 waves x 8
//   groups x 80B, bases on 8 distinct banks -> conflict-free b128 reads),
//   x buf1 at 0x5000 (XOR 0x4000 toggle).
// x path maskless: all 64 lanes gload dwordx2 (8B) + ds_write_b64.
// Chunk order: Wi n0 (init, NO WAIT: x pre-read before the barrier) n1-3,
// then Wh m0-7 (lgkm ladder 5,5,5,5,5,4,3,2,1,0 as audited).
// ---------------------------------------------------------------------------

#define FCHUNK(CNT, A0,A1,B0,B1,C0,C1,D0,D1, H0,H1) \
        "s_waitcnt lgkmcnt(" CNT ")\n" \
        "v_pk_fma_f32 v[32:33], v[" A0 "], v[" H0 "], v[32:33]\n" \
        "v_pk_fma_f32 v[34:35], v[" B0 "], v[" H0 "], v[34:35]\n" \
        "v_pk_fma_f32 v[36:37], v[" C0 "], v[" H0 "], v[36:37]\n" \
        "v_pk_fma_f32 v[38:39], v[" D0 "], v[" H0 "], v[38:39]\n" \
        "v_pk_fma_f32 v[32:33], v[" A1 "], v[" H1 "], v[32:33]\n" \
        "v_pk_fma_f32 v[34:35], v[" B1 "], v[" H1 "], v[34:35]\n" \
        "v_pk_fma_f32 v[36:37], v[" C1 "], v[" H1 "], v[36:37]\n" \
        "v_pk_fma_f32 v[38:39], v[" D1 "], v[" H1 "], v[38:39]\n"

// no-wait chunk (x quads: data drained before the barrier)
#define FCHUNK_NW(A0,A1,B0,B1,C0,C1,D0,D1, H0,H1) \
        "v_pk_fma_f32 v[32:33], v[" A0 "], v[" H0 "], v[32:33]\n" \
        "v_pk_fma_f32 v[34:35], v[" B0 "], v[" H0 "], v[34:35]\n" \
        "v_pk_fma_f32 v[36:37], v[" C0 "], v[" H0 "], v[36:37]\n" \
        "v_pk_fma_f32 v[38:39], v[" D0 "], v[" H0 "], v[38:39]\n" \
        "v_pk_fma_f32 v[32:33], v[" A1 "], v[" H1 "], v[32:33]\n" \
        "v_pk_fma_f32 v[34:35], v[" B1 "], v[" H1 "], v[34:35]\n" \
        "v_pk_fma_f32 v[36:37], v[" C1 "], v[" H1 "], v[36:37]\n" \
        "v_pk_fma_f32 v[38:39], v[" D1 "], v[" H1 "], v[38:39]\n"

#define HSTORE \
        "global_store_dword v25, v30, %[iob]\n" \
        "v_add_u32 v25, 0x40000, v25\n"

// One timestep. XN = x set loaded this step (plane t+2);
// XC = x set loaded last step (plane t+1), ds-written now; VC = vmcnt.
#define FBODY(XN, XC, VC, ST) \
        ST \
        /* x_{t+2} prefetch: all 64 lanes, 8B each; clamp final plane */ \
        "global_load_dwordx2 " XN ", v18, %[xb]\n" \
        "v_add_u32 v18, 0x20000, v18\n" \
        "v_min_u32 v18, %[vxomax], v18\n" \
        /* h quads 0,1 -> S4,S5 */ \
        "ds_read_b128 v[56:59], v16\n" \
        "ds_read_b128 v[60:63], v16 offset:16\n" \
        "s_setprio 1\n" \
        /* Wi n0 (S0, x pre-read): init, NO WAIT */ \
        "v_pk_mul_f32 v[32:33], v[192:193], v[40:41]\n" \
        "v_pk_mul_f32 v[34:35], v[208:209], v[40:41]\n" \
        "v_pk_mul_f32 v[36:37], v[224:225], v[40:41]\n" \
        "v_pk_mul_f32 v[38:39], v[240:241], v[40:41]\n" \
        "v_pk_fma_f32 v[32:33], v[194:195], v[42:43], v[32:33]\n" \
        "v_pk_fma_f32 v[34:35], v[210:211], v[42:43], v[34:35]\n" \
        "v_pk_fma_f32 v[36:37], v[226:227], v[42:43], v[36:37]\n" \
        "v_pk_fma_f32 v[38:39], v[242:243], v[42:43], v[38:39]\n" \
        "ds_read_b128 v[40:43], v16 offset:32\n"   /* q2 -> S0 */ \
        /* Wi n1 (S1) */ \
        FCHUNK_NW("196:197","198:199","212:213","214:215","228:229","230:231","244:245","246:247","44:45","46:47") \
        "ds_read_b128 v[44:47], v16 offset:48\n"   /* q3 -> S1 */ \
        /* Wi n2 (S2) */ \
        FCHUNK_NW("200:201","202:203","216:217","218:219","232:233","234:235","248:249","250:251","48:49","50:51") \
        "ds_read_b128 v[48:51], v16 offset:64\n"   /* q4 -> S2 */ \
        /* Wi n3 (S3) */ \
        FCHUNK_NW("204:205","206:207","220:221","222:223","236:237","238:239","252:253","254:255","52:53","54:55") \
        "ds_read_b128 v[52:55], v16 offset:80\n"   /* q5 -> S3 */ \
        /* Wh m0 (S4=q0) */ \
        FCHUNK("5","64:65","66:67","96:97","98:99","128:129","130:131","160:161","162:163","56:57","58:59") \
        "ds_read_b128 v[56:59], v16 offset:96\n"   /* q6 -> S4 */ \
        /* Wh m1 (S5=q1) */ \
        FCHUNK("5","68:69","70:71","100:101","102:103","132:133","134:135","164:165","166:167","60:61","62:63") \
        "ds_read_b128 v[60:63], v16 offset:112\n"  /* q7 -> S5 */ \
        /* Wh m2-m7 */ \
        FCHUNK("5","72:73","74:75","104:105","106:107","136:137","138:139","168:169","170:171","40:41","42:43") \
        FCHUNK("4","76:77","78:79","108:109","110:111","140:141","142:143","172:173","174:175","44:45","46:47") \
        FCHUNK("3","80:81","82:83","112:113","114:115","144:145","146:147","176:177","178:179","48:49","50:51") \
        FCHUNK("2","84:85","86:87","116:117","118:119","148:149","150:151","180:181","182:183","52:53","54:55") \
        FCHUNK("1","88:89","90:91","120:121","122:123","152:153","154:155","184:185","186:187","56:57","58:59") \
        FCHUNK("0","92:93","94:95","124:125","126:127","156:157","158:159","188:189","190:191","60:61","62:63") \
        "s_setprio 0\n" \
        /* x_{t+1} -> next buffer (all lanes, own-wave region) */ \
        "s_waitcnt vmcnt(" VC ")\n" \
        "ds_write_b64 v24, " XC "\n" \
        "v_xor_b32 v24, 0x4000, v24\n" \
        /* merge pk pairs -> v32,v34,v36,v38 (clean 4-add form) */ \
        "v_add_f32 v32, v32, v33\n" \
        "v_add_f32 v34, v34, v35\n" \
        "v_add_f32 v36, v36, v37\n" \
        "v_add_f32 v38, v38, v39\n" \
        /* xor1, xor2 (producer->DPP gaps >= 3) */ \
        "v_add_f32 v32, v32, v32 quad_perm:[1,0,3,2] row_mask:0xf bank_mask:0xf\n" \
        "v_add_f32 v34, v34, v34 quad_perm:[1,0,3,2] row_mask:0xf bank_mask:0xf\n" \
        "v_add_f32 v36, v36, v36 quad_perm:[1,0,3,2] row_mask:0xf bank_mask:0xf\n" \
        "v_add_f32 v38, v38, v38 quad_perm:[1,0,3,2] row_mask:0xf bank_mask:0xf\n" \
        "v_add_f32 v32, v32, v32 quad_perm:[2,3,0,1] row_mask:0xf bank_mask:0xf\n" \
        "v_add_f32 v34, v34, v34 quad_perm:[2,3,0,1] row_mask:0xf bank_mask:0xf\n" \
        "v_add_f32 v36, v36, v36 quad_perm:[2,3,0,1] row_mask:0xf bank_mask:0xf\n" \
        "v_add_f32 v38, v38, v38 quad_perm:[2,3,0,1] row_mask:0xf bank_mask:0xf\n" \
        /* select-early (kg&3) */ \
        "v_cndmask_b32 v30, v32, v34, %[m0]\n" \
        "v_cndmask_b32 v31, v36, v38, %[m0]\n" \
        "v_cndmask_b32 v30, v30, v31, %[m1]\n" \
        /* DPP crossbar hazard fence, then xor8 */ \
        "s_nop 1\n" \
        "v_add_f32 v30, v30, v30 row_ror:8 row_mask:0xf bank_mask:0xf\n" \
        /* + bh*S ; tanh = 1 - 2*rcp(exp2(arg)+1) */ \
        "v_add_f32 v30, v30, v19\n" \
        "v_exp_f32 v31, v30\n" \
        "s_nop 0\n" \
        "v_add_f32 v31, 1.0, v31\n" \
        "v_rcp_f32 v31, v31\n" \
        "s_nop 0\n" \
        "v_fma_f32 v30, -2.0, v31, 1.0\n" \
        /* masked h LDS write (kg<4) */ \
        "s_and_saveexec_b64 s[84:85], %[msk]\n" \
        "ds_write_b32 v17, v30\n" \
        "s_mov_b64 exec, s[84:85]\n" \
        "v_xor_b32 v17, 0x800, v17\n" \
        /* PRE-BARRIER next-x reads (own region; same-wave DS in-order) */ \
        "ds_read_b128 v[40:43], v26\n" \
        "ds_read_b128 v[44:47], v26 offset:16\n" \
        "ds_read_b128 v[48:51], v26 offset:32\n" \
        "ds_read_b128 v[52:55], v26 offset:48\n" \
        "v_xor_b32 v26, 0x4000, v26\n" \
        "s_waitcnt lgkmcnt(0)\n" \
        "s_barrier\n" \
        "v_xor_b32 v16, 0x800, v16\n"

#define SCALE_PAIR(P) "v_pk_mul_f32 v[" P "], v[" P "], v[26:27]\n"

__global__ __launch_bounds__(512, 2) void rnn_fused_kernel(
    const float* __restrict__ x,  const float* __restrict__ h0,
    const float* __restrict__ Wi, const float* __restrict__ Wh,
    const float* __restrict__ bh, float* __restrict__ out)
{
    // h buf0 [0,0x480) buf1 [0x800,0xC80);
    // x buf0 [0x1000,0x2400) buf1 [0x5000,0x6400)  (XOR 0x4000 toggle:
    // bit 14 constant 0 over buf0 and constant 1 over buf1).
    __shared__ float hbuf[6400];

    const int tid  = threadIdx.x;
    const int b    = blockIdx.x;
    const int lane = tid & 63;
    const int q    = tid >> 6;                       // wave id 0..7
    const int kg   = (lane & 3) | ((lane >> 1) & 4); // 0..7
    const int cg   = ((lane >> 2) & 1) | ((lane >> 3) & 6); // 0..7
    const int col0 = 32 * q + 4 * cg;
    const int col  = col0 + (kg & 3);                // finalize column

    const float* wp  = Wh + (size_t)col0 * HH + kg * 32;  // Wh frag base
    const float* wip = Wi + (size_t)col0 * II + kg * 16;  // Wi frag base
    const float* iob = out + (size_t)b * HH;              // h store base
    const float* xb  = x   + (size_t)b * II;              // x load base
    unsigned hbase = (unsigned)(size_t)&hbuf[0];
    unsigned hvr = hbase + kg * 144;                      // h read base (buf0)
    unsigned hvw = hbase + 0x800 + q * 144 + (4 * cg + (kg & 3)) * 4;
    unsigned xz  = hbase + 0x1000 + q * 640;              // own x region, buf0
    unsigned vxw = xz + ((lane >> 3) * 80) + ((lane & 7) * 8);  // x write
    unsigned vxr = xz + kg * 80;                          // x read base
    unsigned vxo = (unsigned)(lane * 8);                  // x gload ofs, plane 0
    unsigned vxomax = vxo + 511u * 0x20000u;
    unsigned vho = (unsigned)(col * 4);                   // h store ofs
    float bhv = bh[col] * TANH_S;
    unsigned long long m0  = __ballot((lane & 1) != 0);
    unsigned long long m1  = __ballot((lane & 2) != 0);
    unsigned long long msk = __ballot(kg < 4);            // h LDS writers

    // stage h0 into buffer 0 (kg-group layout, stride 36 floats)
    if (tid < HH) hbuf[(tid >> 5) * 36 + (tid & 31)] = h0[(size_t)b * HH + tid];
    __syncthreads();

    asm volatile(
        // ---- Wh fragment: col j quad m -> v[64+32j+4m] ----
        "global_load_dwordx4 v[64:67],   %[wp], off\n"
        "global_load_dwordx4 v[68:71],   %[wp], off offset:16\n"
        "global_load_dwordx4 v[72:75],   %[wp], off offset:32\n"
        "global_load_dwordx4 v[76:79],   %[wp], off offset:48\n"
        "global_load_dwordx4 v[80:83],   %[wp], off offset:64\n"
        "global_load_dwordx4 v[84:87],   %[wp], off offset:80\n"
        "global_load_dwordx4 v[88:91],   %[wp], off offset:96\n"
        "global_load_dwordx4 v[92:95],   %[wp], off offset:112\n"
        "global_load_dwordx4 v[96:99],   %[wp], off offset:1024\n"
        "global_load_dwordx4 v[100:103], %[wp], off offset:1040\n"
        "global_load_dwordx4 v[104:107], %[wp], off offset:1056\n"
        "global_load_dwordx4 v[108:111], %[wp], off offset:1072\n"
        "global_load_dwordx4 v[112:115], %[wp], off offset:1088\n"
        "global_load_dwordx4 v[116:119], %[wp], off offset:1104\n"
        "global_load_dwordx4 v[120:123], %[wp], off offset:1120\n"
        "global_load_dwordx4 v[124:127], %[wp], off offset:1136\n"
        "global_load_dwordx4 v[128:131], %[wp], off offset:2048\n"
        "global_load_dwordx4 v[132:135], %[wp], off offset:2064\n"
        "global_load_dwordx4 v[136:139], %[wp], off offset:2080\n"
        "global_load_dwordx4 v[140:143], %[wp], off offset:2096\n"
        "global_load_dwordx4 v[144:147], %[wp], off offset:2112\n"
        "global_load_dwordx4 v[148:151], %[wp], off offset:2128\n"
        "global_load_dwordx4 v[152:155], %[wp], off offset:2144\n"
        "global_load_dwordx4 v[156:159], %[wp], off offset:2160\n"
        "global_load_dwordx4 v[160:163], %[wp], off offset:3072\n"
        "global_load_dwordx4 v[164:167], %[wp], off offset:3088\n"
        "global_load_dwordx4 v[168:171], %[wp], off offset:3104\n"
        "global_load_dwordx4 v[172:175], %[wp], off offset:3120\n"
        "global_load_dwordx4 v[176:179], %[wp], off offset:3136\n"
        "global_load_dwordx4 v[180:183], %[wp], off offset:3152\n"
        "global_load_dwordx4 v[184:187], %[wp], off offset:3168\n"
        "global_load_dwordx4 v[188:191], %[wp], off offset:3184\n"
        // ---- Wi fragment: col j quad n -> v[192+16j+4n] ----
        "global_load_dwordx4 v[192:195], %[wip], off\n"
        "global_load_dwordx4 v[196:199], %[wip], off offset:16\n"
        "global_load_dwordx4 v[200:203], %[wip], off offset:32\n"
        "global_load_dwordx4 v[204:207], %[wip], off offset:48\n"
        "global_load_dwordx4 v[208:211], %[wip], off offset:512\n"
        "global_load_dwordx4 v[212:215], %[wip], off offset:528\n"
        "global_load_dwordx4 v[216:219], %[wip], off offset:544\n"
        "global_load_dwordx4 v[220:223], %[wip], off offset:560\n"
        "global_load_dwordx4 v[224:227], %[wip], off offset:1024\n"
        "global_load_dwordx4 v[228:231], %[wip], off offset:1040\n"
        "global_load_dwordx4 v[232:235], %[wip], off offset:1056\n"
        "global_load_dwordx4 v[236:239], %[wip], off offset:1072\n"
        "global_load_dwordx4 v[240:243], %[wip], off offset:1536\n"
        "global_load_dwordx4 v[244:247], %[wip], off offset:1552\n"
        "global_load_dwordx4 v[248:251], %[wip], off offset:1568\n"
        "global_load_dwordx4 v[252:255], %[wip], off offset:1584\n"
        "s_waitcnt vmcnt(0)\n"
        // ---- one-time pre-scale of Wh+Wi fragments by 2*log2(e) ----
        "v_mov_b32 v26, 0x4038aa3b\n"
        "v_mov_b32 v27, 0x4038aa3b\n"
        SCALE_PAIR("64:65")   SCALE_PAIR("66:67")   SCALE_PAIR("68:69")   SCALE_PAIR("70:71")
        SCALE_PAIR("72:73")   SCALE_PAIR("74:75")   SCALE_PAIR("76:77")   SCALE_PAIR("78:79")
        SCALE_PAIR("80:81")   SCALE_PAIR("82:83")   SCALE_PAIR("84:85")   SCALE_PAIR("86:87")
        SCALE_PAIR("88:89")   SCALE_PAIR("90:91")   SCALE_PAIR("92:93")   SCALE_PAIR("94:95")
        SCALE_PAIR("96:97")   SCALE_PAIR("98:99")   SCALE_PAIR("100:101") SCALE_PAIR("102:103")
        SCALE_PAIR("104:105") SCALE_PAIR("106:107") SCALE_PAIR("108:109") SCALE_PAIR("110:111")
        SCALE_PAIR("112:113") SCALE_PAIR("114:115") SCALE_PAIR("116:117") SCALE_PAIR("118:119")
        SCALE_PAIR("120:121") SCALE_PAIR("122:123") SCALE_PAIR("124:125") SCALE_PAIR("126:127")
        SCALE_PAIR("128:129") SCALE_PAIR("130:131") SCALE_PAIR("132:133") SCALE_PAIR("134:135")
        SCALE_PAIR("136:137") SCALE_PAIR("138:139") SCALE_PAIR("140:141") SCALE_PAIR("142:143")
        SCALE_PAIR("144:145") SCALE_PAIR("146:147") SCALE_PAIR("148:149") SCALE_PAIR("150:151")
        SCALE_PAIR("152:153") SCALE_PAIR("154:155") SCALE_PAIR("156:157") SCALE_PAIR("158:159")
        SCALE_PAIR("160:161") SCALE_PAIR("162:163") SCALE_PAIR("164:165") SCALE_PAIR("166:167")
        SCALE_PAIR("168:169") SCALE_PAIR("170:171") SCALE_PAIR("172:173") SCALE_PAIR("174:175")
        SCALE_PAIR("176:177") SCALE_PAIR("178:179") SCALE_PAIR("180:181") SCALE_PAIR("182:183")
        SCALE_PAIR("184:185") SCALE_PAIR("186:187") SCALE_PAIR("188:189") SCALE_PAIR("190:191")
        SCALE_PAIR("192:193") SCALE_PAIR("194:195") SCALE_PAIR("196:197") SCALE_PAIR("198:199")
        SCALE_PAIR("200:201") SCALE_PAIR("202:203") SCALE_PAIR("204:205") SCALE_PAIR("206:207")
        SCALE_PAIR("208:209") SCALE_PAIR("210:211") SCALE_PAIR("212:213") SCALE_PAIR("214:215")
        SCALE_PAIR("216:217") SCALE_PAIR("218:219") SCALE_PAIR("220:221") SCALE_PAIR("222:223")
        SCALE_PAIR("224:225") SCALE_PAIR("226:227") SCALE_PAIR("228:229") SCALE_PAIR("230:231")
        SCALE_PAIR("232:233") SCALE_PAIR("234:235") SCALE_PAIR("236:237") SCALE_PAIR("238:239")
        SCALE_PAIR("240:241") SCALE_PAIR("242:243") SCALE_PAIR("244:245") SCALE_PAIR("246:247")
        SCALE_PAIR("248:249") SCALE_PAIR("250:251") SCALE_PAIR("252:253") SCALE_PAIR("254:255")
        // ---- init (v26 repurposed AFTER scaling) ----
        "v_mov_b32 v16, %[hvr]\n"
        "v_mov_b32 v17, %[hvw]\n"
        "v_mov_b32 v18, %[vxo]\n"
        "v_mov_b32 v19, %[bhv]\n"
        "v_mov_b32 v24, %[vxw]\n"
        "v_mov_b32 v25, %[vho]\n"
        "v_mov_b32 v26, %[vxr]\n"
        // ---- prologue x: plane0 -> set0, write buf0, pre-read buf0;
        //      plane1 -> set1; v18 ends at plane 2 ----
        "global_load_dwordx2 v[20:21], v18, %[xb]\n"
        "v_add_u32 v18, 0x20000, v18\n"
        "global_load_dwordx2 v[22:23], v18, %[xb]\n"
        "v_add_u32 v18, 0x20000, v18\n"
        "s_waitcnt vmcnt(1)\n"
        "ds_write_b64 v24, v[20:21]\n"
        "v_xor_b32 v24, 0x4000, v24\n"
        "ds_read_b128 v[40:43], v26\n"
        "ds_read_b128 v[44:47], v26 offset:16\n"
        "ds_read_b128 v[48:51], v26 offset:32\n"
        "ds_read_b128 v[52:55], v26 offset:48\n"
        "v_xor_b32 v26, 0x4000, v26\n"
        "s_waitcnt lgkmcnt(0)\n"
        "s_movk_i32 s82, 0xFF\n"
        // ---- peeled step 0 (no h store; vmcnt(1) = this body's gload) ----
        FBODY("v[20:21]", "v[22:23]", "1", "")
        // ---- peeled step 1 (steady state: hstore + vmcnt(2)) ----
        FBODY("v[22:23]", "v[20:21]", "2", HSTORE)
        "LTOP_%=:\n"
        FBODY("v[20:21]", "v[22:23]", "2", HSTORE)
        FBODY("v[22:23]", "v[20:21]", "2", HSTORE)
        "s_sub_u32 s82, s82, 1\n"
        "s_cmp_lg_u32 s82, 0\n"
        "s_cbranch_scc1 LTOP_%=\n"
        // ---- epilogue: store h_T ----
        "global_store_dword v25, v30, %[iob]\n"
        :
        : [wp] "v"(wp), [wip] "v"(wip), [iob] "s"(iob), [xb] "s"(xb),
          [hvr] "v"(hvr), [hvw] "v"(hvw), [vxo] "v"(vxo),
          [vxomax] "v"(vxomax), [vxw] "v"(vxw), [vxr] "v"(vxr),
          [vho] "v"(vho), [bhv] "v"(bhv),
          [m0] "s"(m0), [m1] "s"(m1), [msk] "s"(msk)
        : "memory", "scc", "s82", "s84", "s85",
          "v16","v17","v18","v19","v20","v21","v22","v23",
          "v24","v25","v26","v27","v28","v29","v30","v31",
          "v32","v33","v34","v35","v36","v37","v38","v39",
          "v40","v41","v42","v43","v44","v45","v46","v47",
          "v48","v49","v50","v51","v52","v53","v54","v55",
          "v56","v57","v58","v59","v60","v61","v62","v63",
          "v64","v65","v66","v67","v68","v69","v70","v71",
          "v72","v73","v74","v75","v76","v77","v78","v79",
          "v80","v81","v82","v83","v84","v85","v86","v87",
          "v88","v89","v90","v91","v92","v93","v94","v95",
          "v96","v97","v98","v99","v100","v101","v102","v103",
          "v104","v105","v106","v107","v108","v109","v110","v111",
          "v112","v113","v114","v115","v116","v117","v118","v119",
          "v120","v121","v122","v123","v124","v125","v126","v127",
          "v128","v129","v130","v131","v132","v133","v134","v135",
          "v136","v137","v138","v139","v140","v141","v142","v143",
          "v144","v145","v146","v147","v148","v149","v150","v151",
          "v152","v153","v154","v155","v156","v157","v158","v159",
          "v160","v161","v162","v163","v164","v165","v166","v167",
          "v168","v169","v170","v171","v172","v173","v174","v175",
          "v176","v177","v178","v179","v180","v181","v182","v183",
          "v184","v185","v186","v187","v188","v189","v190","v191",
          "v192","v193","v194","v195","v196","v197","v198","v199",
          "v200","v201","v202","v203","v204","v205","v206","v207",
          "v208","v209","v210","v211","v212","v213","v214","v215",
          "v216","v217","v218","v219","v220","v221","v222","v223",
          "v224","v225","v226","v227","v228","v229","v230","v231",
          "v232","v233","v234","v235","v236","v237","v238","v239",
          "v240","v241","v242","v243","v244","v245","v246","v247",
          "v248","v249","v250","v251","v252","v253","v254","v255");
}

extern "C" void kernel_launch(void* const* d_in, const int* in_sizes, int n_in,
                              void* d_out, int out_size, void* d_ws, size_t ws_size,
                              hipStream_t stream) {
    const float* x  = (const float*)d_in[0];  // [T,B,I]
    const float* h0 = (const float*)d_in[1];  // [B,H]
    const float* Wi = (const float*)d_in[2];  // [H,I]
    const float* Wh = (const float*)d_in[3];  // [H,H]
    const float* bh = (const float*)d_in[4];  // [H]
    float* out = (float*)d_out;               // [T,B,H]

    rnn_fused_kernel<<<BB, 512, 0, stream>>>(x, h0, Wi, Wh, bh, out);
}